// Round 12
// baseline (552.803 us; speedup 1.0000x reference)
//
#include <hip/hip_runtime.h>
#include <hip/hip_bf16.h>

typedef unsigned short us16;
typedef unsigned int u32;

#define B_   256
#define T_   250
#define IN_  700
#define KP_  704           // K padded
#define H_   256
#define O_   20
#define HK_  1024
#define NPAIR_ (B_ * T_)   // 64000
#define LDP_ 40            // tier-1 LDS pitch
#define CP_  132           // epilogue C-tile pitch (elems)

typedef __attribute__((ext_vector_type(8))) short short8;
typedef __attribute__((ext_vector_type(4))) float f32x4;

__device__ __forceinline__ float bfbits(unsigned int lo16) {
    union { unsigned int i; float f; } v; v.i = lo16 << 16; return v.f;
}
__device__ __forceinline__ float bflo(unsigned int u) {
    union { unsigned int i; float f; } v; v.i = u << 16; return v.f;
}
__device__ __forceinline__ float bfhi(unsigned int u) {
    union { unsigned int i; float f; } v; v.i = u & 0xffff0000u; return v.f;
}
__device__ __forceinline__ us16 f2bfu(float f) {
    __hip_bfloat16 h = __float2bfloat16(f);
    union { __hip_bfloat16 h; us16 u; } c; c.h = h; return c.u;
}
__device__ __forceinline__ float sigm(float x) { return 1.0f / (1.0f + expf(-x)); }
__device__ __forceinline__ int rfl(int v) { return __builtin_amdgcn_readfirstlane(v); }

// tau_n1 uniform in [2,6): bf16 => every value ushort has high byte 0x40.
// (Round-5 counters proved this dataset is fp32.)
__device__ __forceinline__ bool detect_bf16(const us16* __restrict__ taun) {
    int ok = 0;
#pragma unroll
    for (int i = 0; i < 8; i += 2) ok += ((taun[i] >> 8) == 0x40) ? 1 : 0;
    return ok == 4;
}
__device__ __forceinline__ float ldany(const void* __restrict__ p, long i, bool isb) {
    return isb ? bfbits(((const us16*)p)[i]) : ((const float*)p)[i];
}

// async global->LDS, 16B per lane; lds base must be wave-uniform.
__device__ __forceinline__ void async_cp16(const us16* g, us16* l) {
    __builtin_amdgcn_global_load_lds(
        (const __attribute__((address_space(1))) u32*)g,
        (__attribute__((address_space(3))) u32*)l, 16, 0, 0);
}

// ---------------------------------------------------------------------------
// Merged row convert+pad for X and W1 (one launch): [*,700] -> [*,704] bf16.
// One wave per row; float4 loads + uint2 stores (700 = 175x4; chunk 175 = pad).
// ---------------------------------------------------------------------------
__global__ __launch_bounds__(256) void cvt_rows2(
    const void* __restrict__ xin, const void* __restrict__ w1in,
    us16* __restrict__ xout, us16* __restrict__ w1out,
    const us16* __restrict__ taun) {
    const bool isb = detect_bf16(taun);
    const int r = blockIdx.x * 4 + (threadIdx.x >> 6);
    const int l = threadIdx.x & 63;
    const void* in; us16* out; long ibase, obase;
    if (r < NPAIR_) {
        in = xin;  out = xout;  ibase = (long)r * IN_; obase = (long)r * KP_;
    } else {
        const int r2 = r - NPAIR_;
        if (r2 >= HK_) return;
        in = w1in; out = w1out; ibase = (long)r2 * IN_; obase = (long)r2 * KP_;
    }
    for (int c = l; c < 176; c += 64) {
        uint2 o;
        if (c < 175) {
            if (isb) {
                o = *(const uint2*)((const us16*)in + ibase + 4 * c);
            } else {
                float4 f = *(const float4*)((const float*)in + ibase + 4 * c);
                o.x = (u32)f2bfu(f.x) | ((u32)f2bfu(f.y) << 16);
                o.y = (u32)f2bfu(f.z) | ((u32)f2bfu(f.w) << 16);
            }
        } else { o.x = 0u; o.y = 0u; }
        *(uint2*)(out + obase + 4 * c) = o;
    }
}

// ---------------------------------------------------------------------------
__global__ void transpose_to_bf16(const void* __restrict__ in, us16* __restrict__ out,
                                  int R, int C, const us16* __restrict__ taun) {
    const bool isb = detect_bf16(taun);
    __shared__ us16 tile[32][33];
    int c0 = blockIdx.x * 32, r0 = blockIdx.y * 32;
    int tx = threadIdx.x, ty = threadIdx.y;   // block (32,8)
#pragma unroll
    for (int j = 0; j < 32; j += 8) {
        int r = r0 + ty + j, c = c0 + tx;
        if (r < R && c < C) tile[ty + j][tx] = f2bfu(ldany(in, (long)r * C + c, isb));
    }
    __syncthreads();
#pragma unroll
    for (int j = 0; j < 32; j += 8) {
        int c = c0 + ty + j, r = r0 + tx;
        if (c < C && r < R) out[(long)c * R + r] = tile[tx][ty + j];
    }
}

// ---------------------------------------------------------------------------
// Tier-0 GEMM, BM=256: Apre[64000,1024] = Xb[64000,704] · W1b[1024,704]^T.
// 256x128 tile, BK=64, async staging, XOR bank swizzle. vs BM=128: L2->LDS
// traffic 1.44 -> 1.05 GB, barriers per output halved, 64 MFMA per step.
// Wave quadrant: wr = m-half (128 rows), wc = n-half (64 cols); acc[8][4].
// ---------------------------------------------------------------------------
__global__ __launch_bounds__(256) void gemm_bf(
    const us16* __restrict__ Xb, const us16* __restrict__ W1b,
    us16* __restrict__ Apre)
{
    __shared__ __align__(16) us16 smem[24576];   // 49152 B
    us16* As = smem;            // 256 x 64
    us16* Bs = smem + 16384;    // 128 x 64

    const int L  = blockIdx.x;                   // grid 2048 (32 windows of 64)
    const int mt = (L & 7) + ((L >> 6) << 3);    // same-L%8 blocks share m-tile
    const int nt = (L >> 3) & 7;
    if (mt >= NPAIR_ / 256) return;              // 250 m-tiles
    const int m0 = mt * 256, n0 = nt * 128;

    const int tid  = threadIdx.x;
    const int lane = tid & 63;
    const int w    = tid >> 6;
    const int wr   = w >> 1, wc = w & 1;
    const int l16  = lane & 15, quad = lane >> 4;

    // staging: lane = rr*8 + cc; stages global 16B-chunk (cc^rr) of row rr
    const int rr   = lane >> 3;
    const int ccsw = ((lane & 7) ^ rr) * 8;
    const us16* xg[8]; us16* asl[8];
    const us16* wg[4]; us16* bsl[4];
#pragma unroll
    for (int i = 0; i < 8; ++i) {
        const int g = w * 8 + i;                 // A row group 0..31
        xg[i]  = Xb + (long)(m0 + g * 8 + rr) * KP_ + ccsw;
        asl[i] = As + g * 512;                   // wave-uniform base (1024 B)
    }
#pragma unroll
    for (int i = 0; i < 4; ++i) {
        const int g = w * 4 + i;                 // B row group 0..15
        wg[i]  = W1b + (long)(n0 + g * 8 + rr) * KP_ + ccsw;
        bsl[i] = Bs + g * 512;
    }

    f32x4 acc[8][4];
#pragma unroll
    for (int i = 0; i < 8; ++i)
#pragma unroll
        for (int j = 0; j < 4; ++j) acc[i][j] = (f32x4){0.f, 0.f, 0.f, 0.f};

    // frag read offsets with de-swizzle (row&7 == l16&7 for all frag rows)
    const int sw = l16 & 7;
    int aoff0[8], aoff1[8], boff0[4], boff1[4];
#pragma unroll
    for (int i = 0; i < 8; ++i) {
        const int ar = wr * 128 + i * 16 + l16;
        aoff0[i] = ar * 64 + ((quad ^ sw) << 3);
        aoff1[i] = ar * 64 + (((quad + 4) ^ sw) << 3);
    }
#pragma unroll
    for (int j = 0; j < 4; ++j) {
        const int br = wc * 64 + j * 16 + l16;
        boff0[j] = br * 64 + ((quad ^ sw) << 3);
        boff1[j] = br * 64 + (((quad + 4) ^ sw) << 3);
    }

    for (int s = 0; s < 11; ++s) {               // 11 * 64 = 704
        const int kb = s * 64;
        __syncthreads();                         // prev step's frag reads done
#pragma unroll
        for (int i = 0; i < 8; ++i) async_cp16(xg[i] + kb, asl[i]);
#pragma unroll
        for (int i = 0; i < 4; ++i) async_cp16(wg[i] + kb, bsl[i]);
        __syncthreads();                         // drain -> staged data visible

        short8 bfv[4][2];
#pragma unroll
        for (int j = 0; j < 4; ++j) {
            bfv[j][0] = *(const short8*)(Bs + boff0[j]);
            bfv[j][1] = *(const short8*)(Bs + boff1[j]);
        }
#pragma unroll
        for (int i = 0; i < 8; ++i) {
            const short8 a0 = *(const short8*)(As + aoff0[i]);
            const short8 a1 = *(const short8*)(As + aoff1[i]);
#pragma unroll
            for (int j = 0; j < 4; ++j) {
                acc[i][j] = __builtin_amdgcn_mfma_f32_16x16x32_bf16(
                    a0, bfv[j][0], acc[i][j], 0, 0, 0);
                acc[i][j] = __builtin_amdgcn_mfma_f32_16x16x32_bf16(
                    a1, bfv[j][1], acc[i][j], 0, 0, 0);
            }
        }
    }

    // epilogue: two 128-row passes through LDS, coalesced 256 B row writes
    for (int p = 0; p < 2; ++p) {
        __syncthreads();                         // K-loop / prev-pass reads done
        if (wr == p) {
#pragma unroll
            for (int i = 0; i < 8; ++i)
#pragma unroll
                for (int j = 0; j < 4; ++j)
#pragma unroll
                    for (int r = 0; r < 4; ++r)
                        smem[(i * 16 + quad * 4 + r) * CP_ +
                             (wc * 64 + j * 16 + l16)] = f2bfu(acc[i][j][r]);
        }
        __syncthreads();
        for (int r2 = 0; r2 < 32; ++r2) {
            const int row = w * 32 + r2;
            const u32 v = *(const u32*)(smem + row * CP_ + lane * 2);
            *(u32*)(Apre + (long)(m0 + p * 128 + row) * HK_ + n0 + lane * 2) = v;
        }
    }
}

// ---------------------------------------------------------------------------
// Tier-0 phase 2 (round-11 proven): producer-consumer, conflict-free consumer
// reads (lane owns elems [8l,8l+8) u [512+8l,512+8l+8)), register prefetch.
// ---------------------------------------------------------------------------
__global__ __launch_bounds__(256) void dhsfnn_pc(
    const us16* __restrict__ Apre,
    const void* __restrict__ b1,  const void* __restrict__ tau_n1,
    const void* __restrict__ tau_m1,
    const void* __restrict__ b2,  const void* __restrict__ tau_n2,
    const void* __restrict__ tau_m2,
    const void* __restrict__ Wr,  const void* __restrict__ br,
    const void* __restrict__ tau_mr,
    const us16* __restrict__ W2T,      // [presyn 256][elem 1024] bf16
    const int* __restrict__ warmup_p,
    void* __restrict__ out)
{
    __shared__ __align__(16) us16 ring[2][16 * HK_];   // 2 x 32 KB

    const int tid  = threadIdx.x;
    const int lane = tid & 63;
    const int w    = tid >> 6;
    const int b    = blockIdx.x;
    const bool isb = detect_bf16((const us16*)tau_n1);
    const int wu   = *warmup_p;

    const us16* apb = Apre + (long)b * T_ * HK_;

    {   // chunk 0: all 4 waves load
        const uint4* src = (const uint4*)apb;
        uint4* dst = (uint4*)ring[0];
        for (int k = tid; k < 16 * 128; k += 256) dst[k] = src[k];
    }

    float be1[16], cb1[16], ce1[16], be2[16], cb2[16], ce2[16], d1[16], d2[16];
#pragma unroll
    for (int e = 0; e < 16; ++e) {
        const long gi = (e < 8) ? ((long)lane * 8 + e) : (512 + (long)lane * 8 + e - 8);
        const float t1 = sigm(ldany(tau_n1, gi, isb));
        be1[e] = t1; ce1[e] = 1.f - t1; cb1[e] = ce1[e] * ldany(b1, gi, isb);
        const float t2 = sigm(ldany(tau_n2, gi, isb));
        be2[e] = t2; ce2[e] = 1.f - t2; cb2[e] = ce2[e] * ldany(b2, gi, isb);
        d1[e] = 0.f; d2[e] = 0.f;
    }
    float al1[4], al2[4], m1[4], s1[4], m2[4], s2[4];
#pragma unroll
    for (int j = 0; j < 4; ++j) {
        const int n = (j < 2) ? (2 * lane + j) : (128 + 2 * lane + (j - 2));
        al1[j] = sigm(ldany(tau_m1, n, isb));
        al2[j] = sigm(ldany(tau_m2, n, isb));
        m1[j] = 0.f; s1[j] = 0.f; m2[j] = 0.f; s2[j] = 0.f;
    }
    float alr = 0.f, brv = 0.f;
    if (lane < O_) { alr = sigm(ldany(tau_mr, lane, isb)); brv = ldany(br, lane, isb); }
    float mrv = 0.f, accO = 0.f;

    __syncthreads();                     // chunk 0 ready

    for (int c = 0; c < 16; ++c) {
        const int t0 = c * 16;
        const int nst = (T_ - t0 < 16) ? (T_ - t0) : 16;

        if (w != 0) {
            if (c + 1 < 16) {            // producers: load chunk c+1
                const int t1c = (c + 1) * 16;
                const int nn  = ((T_ - t1c < 16) ? (T_ - t1c) : 16) * 128;
                const uint4* src = (const uint4*)(apb + (long)t1c * HK_);
                uint4* dst = (uint4*)ring[(c + 1) & 1];
                for (int k = tid - 64; k < nn; k += 192) dst[k] = src[k];
            }
        } else {
            const us16* rb = ring[c & 1];
            uint4 cLo = *(const uint4*)(rb + lane * 8);
            uint4 cHi = *(const uint4*)(rb + 512 + lane * 8);
            for (int q = 0; q < nst; ++q) {
                uint4 nLo = cLo, nHi = cHi;
                if (q + 1 < nst) {       // prefetch next step's row
                    nLo = *(const uint4*)(rb + (q + 1) * HK_ + lane * 8);
                    nHi = *(const uint4*)(rb + (q + 1) * HK_ + 512 + lane * 8);
                }
                const int t = t0 + q;
                float a[16];
                a[0]=bflo(cLo.x);  a[1]=bfhi(cLo.x);  a[2]=bflo(cLo.y);  a[3]=bfhi(cLo.y);
                a[4]=bflo(cLo.z);  a[5]=bfhi(cLo.z);  a[6]=bflo(cLo.w);  a[7]=bfhi(cLo.w);
                a[8]=bflo(cHi.x);  a[9]=bfhi(cHi.x);  a[10]=bflo(cHi.y); a[11]=bfhi(cHi.y);
                a[12]=bflo(cHi.z); a[13]=bfhi(cHi.z); a[14]=bflo(cHi.w); a[15]=bfhi(cHi.w);

#pragma unroll
                for (int e = 0; e < 16; ++e)
                    d1[e] = be1[e] * d1[e] + cb1[e] + ce1[e] * a[e];

                unsigned long long bal1[4];
#pragma unroll
                for (int j = 0; j < 4; ++j) {
                    const float s = (d1[j*4+0] + d1[j*4+1]) + (d1[j*4+2] + d1[j*4+3]);
                    m1[j] = m1[j] * al1[j] + (1.f - al1[j]) * s - s1[j];
                    s1[j] = (m1[j] > 1.0f) ? 1.f : 0.f;
                    bal1[j] = __ballot(s1[j] > 0.f);
                }

                if ((bal1[0] | bal1[1] | bal1[2] | bal1[3]) != 0ull) {   // rare
                    float g[16];
#pragma unroll
                    for (int e = 0; e < 16; ++e) g[e] = 0.f;
                    for (int j2 = 0; j2 < 4; ++j2) {
                        unsigned long long mm = bal1[j2];
                        while (mm) {
                            const int i = __ffsll(mm) - 1; mm &= mm - 1;
                            const int n = (j2 < 2) ? (2 * i + j2) : (128 + 2 * i + (j2 - 2));
                            const us16* wv = W2T + ((long)n << 10);
                            const uint4 wl = *(const uint4*)(wv + lane * 8);
                            const uint4 wh = *(const uint4*)(wv + 512 + lane * 8);
                            g[0]+=bflo(wl.x);  g[1]+=bfhi(wl.x);  g[2]+=bflo(wl.y);  g[3]+=bfhi(wl.y);
                            g[4]+=bflo(wl.z);  g[5]+=bfhi(wl.z);  g[6]+=bflo(wl.w);  g[7]+=bfhi(wl.w);
                            g[8]+=bflo(wh.x);  g[9]+=bfhi(wh.x);  g[10]+=bflo(wh.y); g[11]+=bfhi(wh.y);
                            g[12]+=bflo(wh.z); g[13]+=bfhi(wh.z); g[14]+=bflo(wh.w); g[15]+=bfhi(wh.w);
                        }
                    }
#pragma unroll
                    for (int e = 0; e < 16; ++e)
                        d2[e] = be2[e] * d2[e] + cb2[e] + ce2[e] * g[e];
                } else {
#pragma unroll
                    for (int e = 0; e < 16; ++e)
                        d2[e] = be2[e] * d2[e] + cb2[e];
                }

                unsigned long long bal2[4];
#pragma unroll
                for (int j = 0; j < 4; ++j) {
                    const float s = (d2[j*4+0] + d2[j*4+1]) + (d2[j*4+2] + d2[j*4+3]);
                    m2[j] = m2[j] * al2[j] + (1.f - al2[j]) * s - s2[j];
                    s2[j] = (m2[j] > 1.0f) ? 1.f : 0.f;
                    bal2[j] = __ballot(s2[j] > 0.f);
                }

                if (lane < O_) {
                    float sum = brv;
                    if ((bal2[0] | bal2[1] | bal2[2] | bal2[3]) != 0ull) {
                        for (int j2 = 0; j2 < 4; ++j2) {
                            unsigned long long mm = bal2[j2];
                            while (mm) {
                                const int i = __ffsll(mm) - 1; mm &= mm - 1;
                                const int n = (j2 < 2) ? (2 * i + j2) : (128 + 2 * i + (j2 - 2));
                                sum += ldany(Wr, (long)lane * H_ + n, isb);
                            }
                        }
                    }
                    mrv = alr * mrv + (1.f - alr) * sum;
                    if (t >= wu) accO += mrv;
                }
                cLo = nLo; cHi = nHi;
            }
        }
        __syncthreads();
    }

    if (w == 0 && lane < O_) {
        const float res = accO / (float)(T_ - wu);
        if (isb) ((us16*)out)[b * O_ + lane] = f2bfu(res);
        else     ((float*)out)[b * O_ + lane] = res;
    }
}

// ===========================================================================
// Tier-1 fallback: round-8 proven pair (fp32-direct GEMM + 1-wave recurrence)
// ===========================================================================
#define GA_LOAD(S, AV, BV) do {                                               \
    const int k0_ = (S) * 32 + half16;                                        \
    if (k0_ + 16 <= IN_) {                                                    \
        if (isb) {                                                            \
            const us16* pa_ = (const us16*)X  + arow + k0_;                   \
            const us16* pb_ = (const us16*)W1 + brow + k0_;                   \
            uint2 a0_ = *(const uint2*)pa_,        a1_ = *(const uint2*)(pa_ + 4);  \
            uint2 a2_ = *(const uint2*)(pa_ + 8),  a3_ = *(const uint2*)(pa_ + 12); \
            uint2 b0_ = *(const uint2*)pb_,        b1_ = *(const uint2*)(pb_ + 4);  \
            uint2 b2_ = *(const uint2*)(pb_ + 8),  b3_ = *(const uint2*)(pb_ + 12); \
            AV[0]=a0_.x; AV[1]=a0_.y; AV[2]=a1_.x; AV[3]=a1_.y;               \
            AV[4]=a2_.x; AV[5]=a2_.y; AV[6]=a3_.x; AV[7]=a3_.y;               \
            BV[0]=b0_.x; BV[1]=b0_.y; BV[2]=b1_.x; BV[3]=b1_.y;               \
            BV[4]=b2_.x; BV[5]=b2_.y; BV[6]=b3_.x; BV[7]=b3_.y;               \
        } else {                                                              \
            const float* pa_ = (const float*)X  + arow + k0_;                 \
            const float* pb_ = (const float*)W1 + brow + k0_;                 \
            float4 fa0_ = *(const float4*)pa_,        fa1_ = *(const float4*)(pa_ + 4);  \
            float4 fa2_ = *(const float4*)(pa_ + 8),  fa3_ = *(const float4*)(pa_ + 12); \
            float4 fb0_ = *(const float4*)pb_,        fb1_ = *(const float4*)(pb_ + 4);  \
            float4 fb2_ = *(const float4*)(pb_ + 8),  fb3_ = *(const float4*)(pb_ + 12); \
            AV[0] = (unsigned)f2bfu(fa0_.x) | ((unsigned)f2bfu(fa0_.y) << 16); \
            AV[1] = (unsigned)f2bfu(fa0_.z) | ((unsigned)f2bfu(fa0_.w) << 16); \
            AV[2] = (unsigned)f2bfu(fa1_.x) | ((unsigned)f2bfu(fa1_.y) << 16); \
            AV[3] = (unsigned)f2bfu(fa1_.z) | ((unsigned)f2bfu(fa1_.w) << 16); \
            AV[4] = (unsigned)f2bfu(fa2_.x) | ((unsigned)f2bfu(fa2_.y) << 16); \
            AV[5] = (unsigned)f2bfu(fa2_.z) | ((unsigned)f2bfu(fa2_.w) << 16); \
            AV[6] = (unsigned)f2bfu(fa3_.x) | ((unsigned)f2bfu(fa3_.y) << 16); \
            AV[7] = (unsigned)f2bfu(fa3_.z) | ((unsigned)f2bfu(fa3_.w) << 16); \
            BV[0] = (unsigned)f2bfu(fb0_.x) | ((unsigned)f2bfu(fb0_.y) << 16); \
            BV[1] = (unsigned)f2bfu(fb0_.z) | ((unsigned)f2bfu(fb0_.w) << 16); \
            BV[2] = (unsigned)f2bfu(fb1_.x) | ((unsigned)f2bfu(fb1_.y) << 16); \
            BV[3] = (unsigned)f2bfu(fb1_.z) | ((unsigned)f2bfu(fb1_.w) << 16); \
            BV[4] = (unsigned)f2bfu(fb2_.x) | ((unsigned)f2bfu(fb2_.y) << 16); \
            BV[5] = (unsigned)f2bfu(fb2_.z) | ((unsigned)f2bfu(fb2_.w) << 16); \
            BV[6] = (unsigned)f2bfu(fb3_.x) | ((unsigned)f2bfu(fb3_.y) << 16); \
            BV[7] = (unsigned)f2bfu(fb3_.z) | ((unsigned)f2bfu(fb3_.w) << 16); \
        }                                                                     \
    } else {                                                                  \
        _Pragma("unroll")                                                     \
        for (int e_ = 0; e_ < 8; ++e_) { AV[e_] = 0u; BV[e_] = 0u; }          \
        _Pragma("unroll")                                                     \
        for (int e_ = 0; e_ < 16; ++e_) {                                     \
            int k_ = k0_ + e_;                                                \
            if (k_ < IN_) {                                                   \
                unsigned va_ = (unsigned)f2bfu(ldany(X,  arow + k_, isb));    \
                unsigned vb_ = (unsigned)f2bfu(ldany(W1, brow + k_, isb));    \
                AV[e_ >> 1] |= va_ << ((e_ & 1) * 16);                        \
                BV[e_ >> 1] |= vb_ << ((e_ & 1) * 16);                        \
            }                                                                 \
        }                                                                     \
    }                                                                         \
} while (0)

#define GA_STORE(AV, BV) do {                                                 \
    uint4 u0_; u0_.x = AV[0]; u0_.y = AV[1]; u0_.z = AV[2]; u0_.w = AV[3];    \
    uint4 u1_; u1_.x = AV[4]; u1_.y = AV[5]; u1_.z = AV[6]; u1_.w = AV[7];    \
    uint4 v0_; v0_.x = BV[0]; v0_.y = BV[1]; v0_.z = BV[2]; v0_.w = BV[3];    \
    uint4 v1_; v1_.x = BV[4]; v1_.y = BV[5]; v1_.z = BV[6]; v1_.w = BV[7];    \
    *(uint4*)asw       = u0_; *(uint4*)(asw + 8) = u1_;                       \
    *(uint4*)bsw       = v0_; *(uint4*)(bsw + 8) = v1_;                       \
} while (0)

#define GA_MFMA() do {                                                        \
    short8 af_[4], bf_[4];                                                    \
    _Pragma("unroll")                                                         \
    for (int i_ = 0; i_ < 4; ++i_) af_[i_] = *(const short8*)(As + aoff[i_]); \
    _Pragma("unroll")                                                         \
    for (int j_ = 0; j_ < 4; ++j_) bf_[j_] = *(const short8*)(Bs + boff[j_]); \
    _Pragma("unroll")                                                         \
    for (int i_ = 0; i_ < 4; ++i_)                                            \
        _Pragma("unroll")                                                     \
        for (int j_ = 0; j_ < 4; ++j_)                                        \
            acc[i_][j_] = __builtin_amdgcn_mfma_f32_16x16x32_bf16(            \
                af_[i_], bf_[j_], acc[i_][j_], 0, 0, 0);                      \
} while (0)

__global__ __launch_bounds__(256) void gemm_apre(
    const void* __restrict__ X, const void* __restrict__ W1,
    const us16* __restrict__ taun, us16* __restrict__ Apre)
{
    const bool isb = detect_bf16(taun);
    __shared__ __align__(16) us16 As[128 * LDP_];
    __shared__ __align__(16) us16 Bs[128 * LDP_];

    const int L  = blockIdx.x;
    const int mt = (L & 7) + ((L >> 6) << 3);
    const int nt = (L >> 3) & 7;
    if (mt >= NPAIR_ / 128) return;
    const int m0 = mt * 128, n0 = nt * 128;

    const int tid  = threadIdx.x;
    const int lane = tid & 63;
    const int w    = tid >> 6;
    const int wr   = w >> 1, wc = w & 1;
    const int l16  = lane & 15, quad = lane >> 4;
    const int ra   = tid >> 1;
    const int half16 = (tid & 1) * 16;

    f32x4 acc[4][4];
#pragma unroll
    for (int i = 0; i < 4; ++i)
#pragma unroll
        for (int j = 0; j < 4; ++j) acc[i][j] = (f32x4){0.f, 0.f, 0.f, 0.f};

    int aoff[4], boff[4];
#pragma unroll
    for (int i = 0; i < 4; ++i) {
        aoff[i] = (wr * 64 + i * 16 + l16) * LDP_ + quad * 8;
        boff[i] = (wc * 64 + i * 16 + l16) * LDP_ + quad * 8;
    }

    const long arow = (long)(m0 + ra) * IN_;
    const long brow = (long)(n0 + ra) * IN_;
    us16* asw = As + ra * LDP_ + half16;
    us16* bsw = Bs + ra * LDP_ + half16;

    unsigned av0[8], bv0[8], av1[8], bv1[8];
    GA_LOAD(0, av0, bv0);

    for (int ss = 0; ss < 11; ++ss) {
        __syncthreads();
        GA_STORE(av0, bv0);
        __syncthreads();
        GA_LOAD(2 * ss + 1, av1, bv1);
        GA_MFMA();
        __syncthreads();
        GA_STORE(av1, bv1);
        __syncthreads();
        if (ss < 10) GA_LOAD(2 * ss + 2, av0, bv0);
        GA_MFMA();
    }

#pragma unroll
    for (int i = 0; i < 4; ++i) {
#pragma unroll
        for (int j = 0; j < 4; ++j) {
            const int gm = m0 + wr * 64 + i * 16 + quad * 4;
            const int gn = n0 + wc * 64 + j * 16 + l16;
            us16* op = Apre + (long)gm * HK_ + gn;
#pragma unroll
            for (int r = 0; r < 4; ++r)
                op[(long)r * HK_] = f2bfu(acc[i][j][r]);
        }
    }
}

__global__ __launch_bounds__(64) void dhsfnn_wave(
    const us16* __restrict__ Apre,
    const void* __restrict__ b1,  const void* __restrict__ tau_n1,
    const void* __restrict__ tau_m1,
    const void* __restrict__ b2,  const void* __restrict__ tau_n2,
    const void* __restrict__ tau_m2,
    const void* __restrict__ Wr,  const void* __restrict__ br,
    const void* __restrict__ tau_mr,
    const us16* __restrict__ W2T,
    const int* __restrict__ warmup_p,
    void* __restrict__ out)
{
    const int lane = threadIdx.x;
    const int b    = blockIdx.x;
    const bool isb = detect_bf16((const us16*)tau_n1);
    const int wu   = *warmup_p;

    float be1[16], cb1[16], be2[16], cb2[16], d1[16], d2[16];
#pragma unroll
    for (int e = 0; e < 16; ++e) {
        const long gi = (long)lane * 16 + e;
        const float t1 = sigm(ldany(tau_n1, gi, isb));
        be1[e] = t1; cb1[e] = (1.f - t1) * ldany(b1, gi, isb);
        const float t2 = sigm(ldany(tau_n2, gi, isb));
        be2[e] = t2; cb2[e] = (1.f - t2) * ldany(b2, gi, isb);
        d1[e] = 0.f; d2[e] = 0.f;
    }
    float al1[4], al2[4], m1[4], s1[4], m2[4], s2[4];
#pragma unroll
    for (int j = 0; j < 4; ++j) {
        al1[j] = sigm(ldany(tau_m1, lane * 4 + j, isb));
        al2[j] = sigm(ldany(tau_m2, lane * 4 + j, isb));
        m1[j] = 0.f; s1[j] = 0.f; m2[j] = 0.f; s2[j] = 0.f;
    }
    float alr = 0.f, brv = 0.f;
    if (lane < O_) { alr = sigm(ldany(tau_mr, lane, isb)); brv = ldany(br, lane, isb); }
    float mrv = 0.f, accO = 0.f;

    const us16* ap = Apre + (long)b * T_ * HK_ + lane * 16;

    auto wstep = [&](int t, uint4 lo, uint4 hi) {
        float a[16];
        a[0]=bflo(lo.x);  a[1]=bfhi(lo.x);  a[2]=bflo(lo.y);  a[3]=bfhi(lo.y);
        a[4]=bflo(lo.z);  a[5]=bfhi(lo.z);  a[6]=bflo(lo.w);  a[7]=bfhi(lo.w);
        a[8]=bflo(hi.x);  a[9]=bfhi(hi.x);  a[10]=bflo(hi.y); a[11]=bfhi(hi.y);
        a[12]=bflo(hi.z); a[13]=bfhi(hi.z); a[14]=bflo(hi.w); a[15]=bfhi(hi.w);
#pragma unroll
        for (int e = 0; e < 16; ++e)
            d1[e] = be1[e] * d1[e] + cb1[e] + (1.f - be1[e]) * a[e];
        unsigned long long bal1[4];
#pragma unroll
        for (int j = 0; j < 4; ++j) {
            const float s = (d1[j*4+0] + d1[j*4+1]) + (d1[j*4+2] + d1[j*4+3]);
            m1[j] = m1[j] * al1[j] + (1.f - al1[j]) * s - s1[j];
            s1[j] = (m1[j] > 1.0f) ? 1.f : 0.f;
            bal1[j] = __ballot(s1[j] > 0.f);
        }
        if ((bal1[0] | bal1[1] | bal1[2] | bal1[3]) != 0ull) {
            float g[16];
#pragma unroll
            for (int e = 0; e < 16; ++e) g[e] = 0.f;
            for (int j2 = 0; j2 < 4; ++j2) {
                unsigned long long mm = bal1[j2];
                while (mm) {
                    const int i = __ffsll(mm) - 1; mm &= mm - 1;
                    const us16* wv = W2T + ((long)(i * 4 + j2) << 10) + lane * 16;
                    const uint4 wl = *(const uint4*)wv;
                    const uint4 wh = *(const uint4*)(wv + 8);
                    g[0]+=bflo(wl.x);  g[1]+=bfhi(wl.x);  g[2]+=bflo(wl.y);  g[3]+=bfhi(wl.y);
                    g[4]+=bflo(wl.z);  g[5]+=bfhi(wl.z);  g[6]+=bflo(wl.w);  g[7]+=bfhi(wl.w);
                    g[8]+=bflo(wh.x);  g[9]+=bfhi(wh.x);  g[10]+=bflo(wh.y); g[11]+=bfhi(wh.y);
                    g[12]+=bflo(wh.z); g[13]+=bfhi(wh.z); g[14]+=bflo(wh.w); g[15]+=bfhi(wh.w);
                }
            }
#pragma unroll
            for (int e = 0; e < 16; ++e)
                d2[e] = be2[e] * d2[e] + cb2[e] + (1.f - be2[e]) * g[e];
        } else {
#pragma unroll
            for (int e = 0; e < 16; ++e)
                d2[e] = be2[e] * d2[e] + cb2[e];
        }
        unsigned long long bal2[4];
#pragma unroll
        for (int j = 0; j < 4; ++j) {
            const float s = (d2[j*4+0] + d2[j*4+1]) + (d2[j*4+2] + d2[j*4+3]);
            m2[j] = m2[j] * al2[j] + (1.f - al2[j]) * s - s2[j];
            s2[j] = (m2[j] > 1.0f) ? 1.f : 0.f;
            bal2[j] = __ballot(s2[j] > 0.f);
        }
        if (lane < O_) {
            float sum = brv;
            if ((bal2[0] | bal2[1] | bal2[2] | bal2[3]) != 0ull) {
                for (int j2 = 0; j2 < 4; ++j2) {
                    unsigned long long mm = bal2[j2];
                    while (mm) {
                        const int i = __ffsll(mm) - 1; mm &= mm - 1;
                        sum += ldany(Wr, (long)lane * H_ + (i * 4 + j2), isb);
                    }
                }
            }
            mrv = alr * mrv + (1.f - alr) * sum;
            if (t >= wu) accO += mrv;
        }
    };

    uint4 q0a = *(const uint4*)(ap);
    uint4 q0b = *(const uint4*)(ap + 8);
    uint4 q1a = *(const uint4*)(ap + HK_);
    uint4 q1b = *(const uint4*)(ap + HK_ + 8);
    uint4 q2a = *(const uint4*)(ap + 2 * HK_);
    uint4 q2b = *(const uint4*)(ap + 2 * HK_ + 8);
    uint4 q3a = *(const uint4*)(ap + 3 * HK_);
    uint4 q3b = *(const uint4*)(ap + 3 * HK_ + 8);

    int t = 0;
    for (int it = 0; it < 62; ++it) {
        wstep(t + 0, q0a, q0b);
        q0a = *(const uint4*)(ap + (long)(t + 4) * HK_);
        q0b = *(const uint4*)(ap + (long)(t + 4) * HK_ + 8);
        wstep(t + 1, q1a, q1b);
        if (t + 5 < T_) {
            q1a = *(const uint4*)(ap + (long)(t + 5) * HK_);
            q1b = *(const uint4*)(ap + (long)(t + 5) * HK_ + 8);
        }
        wstep(t + 2, q2a, q2b);
        if (t + 6 < T_) {
            q2a = *(const uint4*)(ap + (long)(t + 6) * HK_);
            q2b = *(const uint4*)(ap + (long)(t + 6) * HK_ + 8);
        }
        wstep(t + 3, q3a, q3b);
        if (t + 7 < T_) {
            q3a = *(const uint4*)(ap + (long)(t + 7) * HK_);
            q3b = *(const uint4*)(ap + (long)(t + 7) * HK_ + 8);
        }
        t += 4;
    }
    wstep(248, q0a, q0b);
    wstep(249, q1a, q1b);

    if (lane < O_) {
        const float res = accO / (float)(T_ - wu);
        if (isb) ((us16*)out)[b * O_ + lane] = f2bfu(res);
        else     ((float*)out)[b * O_ + lane] = res;
    }
}

// ---------------------------------------------------------------------------
// Tier-3 fallback: no workspace at all (round-2 proven).
// ---------------------------------------------------------------------------
__global__ __launch_bounds__(256) void dhsfnn_fb(
    const void* __restrict__ x,  const void* __restrict__ W1,
    const void* __restrict__ b1, const void* __restrict__ tau_n1,
    const void* __restrict__ tau_m1,
    const void* __restrict__ W2, const void* __restrict__ b2,
    const void* __restrict__ tau_n2, const void* __restrict__ tau_m2,
    const void* __restrict__ Wr, const void* __restrict__ br,
    const void* __restrict__ tau_mr,
    const int* __restrict__ warmup_p,
    void* __restrict__ out)
{
    __shared__ us16 list1[1024];
    __shared__ us16 list2[256];
    __shared__ us16 list3[256];
    __shared__ int n1s, n2s, n3s;

    const int tid = threadIdx.x;
    const int b   = blockIdx.x;
    const int h   = tid;
    const bool isb = detect_bf16((const us16*)tau_n1);
    const int wu  = *warmup_p;

    const float be1_0 = sigm(ldany(tau_n1, 4 * h + 0, isb));
    const float be1_1 = sigm(ldany(tau_n1, 4 * h + 1, isb));
    const float be1_2 = sigm(ldany(tau_n1, 4 * h + 2, isb));
    const float be1_3 = sigm(ldany(tau_n1, 4 * h + 3, isb));
    const float bi1_0 = ldany(b1, 4 * h + 0, isb), bi1_1 = ldany(b1, 4 * h + 1, isb);
    const float bi1_2 = ldany(b1, 4 * h + 2, isb), bi1_3 = ldany(b1, 4 * h + 3, isb);
    const float al1 = sigm(ldany(tau_m1, h, isb));
    const float be2_0 = sigm(ldany(tau_n2, 4 * h + 0, isb));
    const float be2_1 = sigm(ldany(tau_n2, 4 * h + 1, isb));
    const float be2_2 = sigm(ldany(tau_n2, 4 * h + 2, isb));
    const float be2_3 = sigm(ldany(tau_n2, 4 * h + 3, isb));
    const float bi2_0 = ldany(b2, 4 * h + 0, isb), bi2_1 = ldany(b2, 4 * h + 1, isb);
    const float bi2_2 = ldany(b2, 4 * h + 2, isb), bi2_3 = ldany(b2, 4 * h + 3, isb);
    const float al2 = sigm(ldany(tau_m2, h, isb));
    float alr = 0.f, brv = 0.f;
    if (h < O_) { alr = sigm(ldany(tau_mr, h, isb)); brv = ldany(br, h, isb); }

    float d1_0 = 0.f, d1_1 = 0.f, d1_2 = 0.f, d1_3 = 0.f, m1v = 0.f, s1f = 0.f;
    float d2_0 = 0.f, d2_1 = 0.f, d2_2 = 0.f, d2_3 = 0.f, m2v = 0.f, s2f = 0.f;
    float mrv = 0.f, accO = 0.f;

    const long xbase = (long)b * T_ * IN_;
    float xv0 = ldany(x, xbase + tid, isb);
    float xv1 = ldany(x, xbase + tid + 256, isb);
    float xv2 = (tid + 512 < IN_) ? ldany(x, xbase + tid + 512, isb) : 0.f;

    for (int t = 0; t < T_; ++t) {
        const bool p0 = xv0 != 0.f, p1 = xv1 != 0.f, p2 = xv2 != 0.f;
        if (t + 1 < T_) {
            const long nbx = xbase + (long)(t + 1) * IN_;
            xv0 = ldany(x, nbx + tid, isb);
            xv1 = ldany(x, nbx + tid + 256, isb);
            xv2 = (tid + 512 < IN_) ? ldany(x, nbx + tid + 512, isb) : 0.f;
        }
        __syncthreads();
        if (tid == 0) { n1s = 0; n2s = 0; n3s = 0; }
        __syncthreads();
        if (p0) { int p = atomicAdd(&n1s, 1); list1[p & 1023] = (us16)tid; }
        if (p1) { int p = atomicAdd(&n1s, 1); list1[p & 1023] = (us16)(tid + 256); }
        if (p2) { int p = atomicAdd(&n1s, 1); list1[p & 1023] = (us16)(tid + 512); }
        __syncthreads();
        int n1 = n1s; n1 = (n1 < 1024) ? n1 : 1024;

        float a0 = 0.f, a1 = 0.f, a2 = 0.f, a3 = 0.f;
#pragma unroll 2
        for (int idx = 0; idx < n1; ++idx) {
            int i = rfl((int)list1[idx]);
            i = (i < IN_) ? i : (IN_ - 1);
            long r = (long)(h * 4) * IN_ + i;
            a0 += ldany(W1, r, isb);
            a1 += ldany(W1, r + IN_, isb);
            a2 += ldany(W1, r + 2 * IN_, isb);
            a3 += ldany(W1, r + 3 * IN_, isb);
        }
        d1_0 = be1_0 * d1_0 + (1.f - be1_0) * (bi1_0 + a0);
        d1_1 = be1_1 * d1_1 + (1.f - be1_1) * (bi1_1 + a1);
        d1_2 = be1_2 * d1_2 + (1.f - be1_2) * (bi1_2 + a2);
        d1_3 = be1_3 * d1_3 + (1.f - be1_3) * (bi1_3 + a3);
        m1v = m1v * al1 + (1.f - al1) * (d1_0 + d1_1 + d1_2 + d1_3) - s1f;
        s1f = (m1v > 1.0f) ? 1.f : 0.f;

        if (s1f > 0.f) { int p = atomicAdd(&n2s, 1); list2[p & 255] = (us16)tid; }
        __syncthreads();
        int n2 = n2s; n2 = (n2 < 256) ? n2 : 256;

        a0 = 0.f; a1 = 0.f; a2 = 0.f; a3 = 0.f;
#pragma unroll 2
        for (int idx = 0; idx < n2; ++idx) {
            int i = rfl((int)list2[idx]);
            i = (i < H_) ? i : (H_ - 1);
            long r = (long)(h * 4) * H_ + i;
            a0 += ldany(W2, r, isb);
            a1 += ldany(W2, r + H_, isb);
            a2 += ldany(W2, r + 2 * H_, isb);
            a3 += ldany(W2, r + 3 * H_, isb);
        }
        d2_0 = be2_0 * d2_0 + (1.f - be2_0) * (bi2_0 + a0);
        d2_1 = be2_1 * d2_1 + (1.f - be2_1) * (bi2_1 + a1);
        d2_2 = be2_2 * d2_2 + (1.f - be2_2) * (bi2_2 + a2);
        d2_3 = be2_3 * d2_3 + (1.f - be2_3) * (bi2_3 + a3);
        m2v = m2v * al2 + (1.f - al2) * (d2_0 + d2_1 + d2_2 + d2_3) - s2f;
        s2f = (m2v > 1.0f) ? 1.f : 0.f;

        if (s2f > 0.f) { int p = atomicAdd(&n3s, 1); list3[p & 255] = (us16)tid; }
        __syncthreads();
        int n3 = n3s; n3 = (n3 < 256) ? n3 : 256;

        if (h < O_) {
            float sum = brv;
            for (int idx = 0; idx < n3; ++idx) {
                int j = (int)list3[idx];
                j = (j < H_) ? j : (H_ - 1);
                sum += ldany(Wr, (long)h * H_ + j, isb);
            }
            mrv = alr * mrv + (1.f - alr) * sum;
            if (t >= wu) accO += mrv;
        }
    }
    if (h < O_) {
        float res = accO / (float)(T_ - wu);
        if (isb) ((us16*)out)[b * O_ + h] = f2bfu(res);
        else     ((float*)out)[b * O_ + h] = res;
    }
}

// ---------------------------------------------------------------------------
extern "C" void kernel_launch(void* const* d_in, const int* in_sizes, int n_in,
                              void* d_out, int out_size, void* d_ws, size_t ws_size,
                              hipStream_t stream) {
    const void* x      = d_in[0];
    const void* W1     = d_in[1];
    const void* b1     = d_in[2];
    const void* tau_n1 = d_in[3];
    const void* tau_m1 = d_in[4];
    const void* W2     = d_in[5];
    const void* b2     = d_in[6];
    const void* tau_n2 = d_in[7];
    const void* tau_m2 = d_in[8];
    const void* Wr     = d_in[9];
    const void* br     = d_in[10];
    const void* tau_mr = d_in[11];
    const int*  warmup = (const int*)d_in[12];

    const size_t w2t_bytes  = (size_t)H_ * HK_ * 2;            //     524,288
    const size_t xbf_bytes  = (size_t)NPAIR_ * KP_ * 2;        //  90,112,000
    const size_t w1b_bytes  = (size_t)HK_ * KP_ * 2;           //   1,441,792
    const size_t apre_bytes = (size_t)NPAIR_ * HK_ * 2;        // 131,072,000

    const bool tier0 = (d_ws != nullptr &&
                        ws_size >= w2t_bytes + xbf_bytes + w1b_bytes + apre_bytes);
    const bool tier1 = (d_ws != nullptr && ws_size >= w2t_bytes + apre_bytes);

    dim3 blk(32, 8);
    if (tier0) {
        us16* W2T  = (us16*)d_ws;
        us16* Xbf  = (us16*)((char*)d_ws + w2t_bytes);
        us16* W1bf = (us16*)((char*)d_ws + w2t_bytes + xbf_bytes);
        us16* Apre = (us16*)((char*)d_ws + w2t_bytes + xbf_bytes + w1b_bytes);
        cvt_rows2<<<(NPAIR_ + HK_) / 4, 256, 0, stream>>>(
            x, W1, Xbf, W1bf, (const us16*)tau_n1);
        transpose_to_bf16<<<dim3((H_ + 31) / 32, (HK_ + 31) / 32), blk, 0, stream>>>(
            W2, W2T, HK_, H_, (const us16*)tau_n1);
        gemm_bf<<<2048, 256, 0, stream>>>(Xbf, W1bf, Apre);
        dhsfnn_pc<<<B_, 256, 0, stream>>>(
            Apre, b1, tau_n1, tau_m1, b2, tau_n2, tau_m2,
            Wr, br, tau_mr, W2T, warmup, d_out);
    } else if (tier1) {
        us16* W2T  = (us16*)d_ws;
        us16* Apre = (us16*)((char*)d_ws + w2t_bytes);
        transpose_to_bf16<<<dim3((H_ + 31) / 32, (HK_ + 31) / 32), blk, 0, stream>>>(
            W2, W2T, HK_, H_, (const us16*)tau_n1);
        gemm_apre<<<4096, 256, 0, stream>>>(x, W1, (const us16*)tau_n1, Apre);
        dhsfnn_wave<<<B_, 64, 0, stream>>>(
            Apre, b1, tau_n1, tau_m1, b2, tau_n2, tau_m2,
            Wr, br, tau_mr, W2T, warmup, d_out);
    } else {
        dhsfnn_fb<<<B_, 256, 0, stream>>>(x, W1, b1, tau_n1, tau_m1,
                                          W2, b2, tau_n2, tau_m2,
                                          Wr, br, tau_mr, warmup, d_out);
    }
}

// Round 13
// 480.626 us; speedup vs baseline: 1.1502x; 1.1502x over previous
//
#include <hip/hip_runtime.h>
#include <hip/hip_bf16.h>

typedef unsigned short us16;
typedef unsigned int u32;

#define B_   256
#define T_   250
#define IN_  700
#define KP_  704           // K padded
#define H_   256
#define O_   20
#define HK_  1024
#define NPAIR_ (B_ * T_)   // 64000
#define LDP_ 40            // tier-1 LDS pitch
#define CP_  132           // epilogue C-tile pitch (elems)

typedef __attribute__((ext_vector_type(8))) short short8;
typedef __attribute__((ext_vector_type(4))) float f32x4;

__device__ __forceinline__ float bfbits(unsigned int lo16) {
    union { unsigned int i; float f; } v; v.i = lo16 << 16; return v.f;
}
__device__ __forceinline__ float bflo(unsigned int u) {
    union { unsigned int i; float f; } v; v.i = u << 16; return v.f;
}
__device__ __forceinline__ float bfhi(unsigned int u) {
    union { unsigned int i; float f; } v; v.i = u & 0xffff0000u; return v.f;
}
__device__ __forceinline__ us16 f2bfu(float f) {
    __hip_bfloat16 h = __float2bfloat16(f);
    union { __hip_bfloat16 h; us16 u; } c; c.h = h; return c.u;
}
__device__ __forceinline__ float sigm(float x) { return 1.0f / (1.0f + expf(-x)); }
__device__ __forceinline__ int rfl(int v) { return __builtin_amdgcn_readfirstlane(v); }

// tau_n1 uniform in [2,6): bf16 => every value ushort has high byte 0x40.
// (Round-5 counters proved this dataset is fp32.)
__device__ __forceinline__ bool detect_bf16(const us16* __restrict__ taun) {
    int ok = 0;
#pragma unroll
    for (int i = 0; i < 8; i += 2) ok += ((taun[i] >> 8) == 0x40) ? 1 : 0;
    return ok == 4;
}
__device__ __forceinline__ float ldany(const void* __restrict__ p, long i, bool isb) {
    return isb ? bfbits(((const us16*)p)[i]) : ((const float*)p)[i];
}

// async global->LDS, 16B per lane; lds base must be wave-uniform.
__device__ __forceinline__ void async_cp16(const us16* g, us16* l) {
    __builtin_amdgcn_global_load_lds(
        (const __attribute__((address_space(1))) u32*)g,
        (__attribute__((address_space(3))) u32*)l, 16, 0, 0);
}

// ---------------------------------------------------------------------------
// Merged row convert+pad for X and W1 (one launch): [*,700] -> [*,704] bf16.
// One wave per row; float4 loads + uint2 stores (700 = 175x4; chunk 175 = pad).
// ---------------------------------------------------------------------------
__global__ __launch_bounds__(256) void cvt_rows2(
    const void* __restrict__ xin, const void* __restrict__ w1in,
    us16* __restrict__ xout, us16* __restrict__ w1out,
    const us16* __restrict__ taun) {
    const bool isb = detect_bf16(taun);
    const int r = blockIdx.x * 4 + (threadIdx.x >> 6);
    const int l = threadIdx.x & 63;
    const void* in; us16* out; long ibase, obase;
    if (r < NPAIR_) {
        in = xin;  out = xout;  ibase = (long)r * IN_; obase = (long)r * KP_;
    } else {
        const int r2 = r - NPAIR_;
        if (r2 >= HK_) return;
        in = w1in; out = w1out; ibase = (long)r2 * IN_; obase = (long)r2 * KP_;
    }
    for (int c = l; c < 176; c += 64) {
        uint2 o;
        if (c < 175) {
            if (isb) {
                o = *(const uint2*)((const us16*)in + ibase + 4 * c);
            } else {
                float4 f = *(const float4*)((const float*)in + ibase + 4 * c);
                o.x = (u32)f2bfu(f.x) | ((u32)f2bfu(f.y) << 16);
                o.y = (u32)f2bfu(f.z) | ((u32)f2bfu(f.w) << 16);
            }
        } else { o.x = 0u; o.y = 0u; }
        *(uint2*)(out + obase + 4 * c) = o;
    }
}

// ---------------------------------------------------------------------------
__global__ void transpose_to_bf16(const void* __restrict__ in, us16* __restrict__ out,
                                  int R, int C, const us16* __restrict__ taun) {
    const bool isb = detect_bf16(taun);
    __shared__ us16 tile[32][33];
    int c0 = blockIdx.x * 32, r0 = blockIdx.y * 32;
    int tx = threadIdx.x, ty = threadIdx.y;   // block (32,8)
#pragma unroll
    for (int j = 0; j < 32; j += 8) {
        int r = r0 + ty + j, c = c0 + tx;
        if (r < R && c < C) tile[ty + j][tx] = f2bfu(ldany(in, (long)r * C + c, isb));
    }
    __syncthreads();
#pragma unroll
    for (int j = 0; j < 32; j += 8) {
        int c = c0 + ty + j, r = r0 + tx;
        if (c < C && r < R) out[(long)c * R + r] = tile[tx][ty + j];
    }
}

// ---------------------------------------------------------------------------
// Tier-0 GEMM (round-11 proven config — BM=128 is the occupancy sweet spot;
// BM=256 regressed 114->186 us at 1 block/CU):
// Apre[64000,1024] = Xb[64000,704] · W1b[1024,704]^T, bf16, BK=64,
// async global_load_lds staging, XOR bank swizzle, LDS-staged epilogue.
// ---------------------------------------------------------------------------
__global__ __launch_bounds__(256) void gemm_bf(
    const us16* __restrict__ Xb, const us16* __restrict__ W1b,
    us16* __restrict__ Apre)
{
    __shared__ __align__(16) us16 smem[128 * CP_];   // 33792 B; K-loop uses 32 KB
    us16* As = smem;                                 // 128 x 64
    us16* Bs = smem + 128 * 64;                      // 128 x 64

    const int L  = blockIdx.x;
    const int mt = (L & 7) + ((L >> 6) << 3);
    const int nt = (L >> 3) & 7;
    if (mt >= NPAIR_ / 128) return;
    const int m0 = mt * 128, n0 = nt * 128;

    const int tid  = threadIdx.x;
    const int lane = tid & 63;
    const int w    = tid >> 6;
    const int wr   = w >> 1, wc = w & 1;
    const int l16  = lane & 15, quad = lane >> 4;

    // staging: lane = rr*8 + cc; stages global 16B-chunk (cc^rr) of row rr
    const int rr    = lane >> 3;
    const int ccsw  = ((lane & 7) ^ rr) * 8;         // swizzled chunk start (elems)
    const us16* xg[4]; const us16* wg[4];
    us16* asl[4]; us16* bsl[4];
#pragma unroll
    for (int i = 0; i < 4; ++i) {
        const int blkrow = (w * 4 + i) * 8;
        xg[i]  = Xb  + (long)(m0 + blkrow + rr) * KP_ + ccsw;
        wg[i]  = W1b + (long)(n0 + blkrow + rr) * KP_ + ccsw;
        asl[i] = As + (w * 4 + i) * 512;             // wave-uniform base (1024 B)
        bsl[i] = Bs + (w * 4 + i) * 512;
    }

    f32x4 acc[4][4];
#pragma unroll
    for (int i = 0; i < 4; ++i)
#pragma unroll
        for (int j = 0; j < 4; ++j) acc[i][j] = (f32x4){0.f, 0.f, 0.f, 0.f};

    const int sw = l16 & 7;
    int aoff0[4], aoff1[4], boff0[4], boff1[4];
#pragma unroll
    for (int i = 0; i < 4; ++i) {
        const int ar = wr * 64 + i * 16 + l16;
        const int br = wc * 64 + i * 16 + l16;
        aoff0[i] = ar * 64 + ((quad ^ sw) << 3);
        aoff1[i] = ar * 64 + (((quad + 4) ^ sw) << 3);
        boff0[i] = br * 64 + ((quad ^ sw) << 3);
        boff1[i] = br * 64 + (((quad + 4) ^ sw) << 3);
    }

    for (int s = 0; s < 11; ++s) {             // 11 * 64 = 704
        const int kb = s * 64;
        __syncthreads();                       // prev step's frag reads done
#pragma unroll
        for (int i = 0; i < 4; ++i) async_cp16(xg[i] + kb, asl[i]);
#pragma unroll
        for (int i = 0; i < 4; ++i) async_cp16(wg[i] + kb, bsl[i]);
        __syncthreads();                       // drain -> staged data visible

        short8 af[4][2], bfv[4][2];
#pragma unroll
        for (int i = 0; i < 4; ++i) {
            af[i][0]  = *(const short8*)(As + aoff0[i]);
            af[i][1]  = *(const short8*)(As + aoff1[i]);
            bfv[i][0] = *(const short8*)(Bs + boff0[i]);
            bfv[i][1] = *(const short8*)(Bs + boff1[i]);
        }
#pragma unroll
        for (int h = 0; h < 2; ++h)
#pragma unroll
            for (int i = 0; i < 4; ++i)
#pragma unroll
                for (int j = 0; j < 4; ++j)
                    acc[i][j] = __builtin_amdgcn_mfma_f32_16x16x32_bf16(
                        af[i][h], bfv[j][h], acc[i][j], 0, 0, 0);
    }

    // epilogue: stage C-tile in LDS, write coalesced 256 B rows
    __syncthreads();
#pragma unroll
    for (int i = 0; i < 4; ++i)
#pragma unroll
        for (int j = 0; j < 4; ++j)
#pragma unroll
            for (int r = 0; r < 4; ++r)
                smem[(wr * 64 + i * 16 + quad * 4 + r) * CP_ +
                     (wc * 64 + j * 16 + l16)] = f2bfu(acc[i][j][r]);
    __syncthreads();
    for (int r2 = 0; r2 < 32; ++r2) {
        const int row = w * 32 + r2;
        const u32 v = *(const u32*)(smem + row * CP_ + lane * 2);
        *(u32*)(Apre + (long)(m0 + row) * HK_ + n0 + lane * 2) = v;
    }
}

// ---------------------------------------------------------------------------
// Tier-0 phase 2 (round-11 proven): producer-consumer, conflict-free consumer
// reads (lane owns elems [8l,8l+8) u [512+8l,512+8l+8)), register prefetch.
// ---------------------------------------------------------------------------
__global__ __launch_bounds__(256) void dhsfnn_pc(
    const us16* __restrict__ Apre,
    const void* __restrict__ b1,  const void* __restrict__ tau_n1,
    const void* __restrict__ tau_m1,
    const void* __restrict__ b2,  const void* __restrict__ tau_n2,
    const void* __restrict__ tau_m2,
    const void* __restrict__ Wr,  const void* __restrict__ br,
    const void* __restrict__ tau_mr,
    const us16* __restrict__ W2T,      // [presyn 256][elem 1024] bf16
    const int* __restrict__ warmup_p,
    void* __restrict__ out)
{
    __shared__ __align__(16) us16 ring[2][16 * HK_];   // 2 x 32 KB

    const int tid  = threadIdx.x;
    const int lane = tid & 63;
    const int w    = tid >> 6;
    const int b    = blockIdx.x;
    const bool isb = detect_bf16((const us16*)tau_n1);
    const int wu   = *warmup_p;

    const us16* apb = Apre + (long)b * T_ * HK_;

    {   // chunk 0: all 4 waves load
        const uint4* src = (const uint4*)apb;
        uint4* dst = (uint4*)ring[0];
        for (int k = tid; k < 16 * 128; k += 256) dst[k] = src[k];
    }

    float be1[16], cb1[16], ce1[16], be2[16], cb2[16], ce2[16], d1[16], d2[16];
#pragma unroll
    for (int e = 0; e < 16; ++e) {
        const long gi = (e < 8) ? ((long)lane * 8 + e) : (512 + (long)lane * 8 + e - 8);
        const float t1 = sigm(ldany(tau_n1, gi, isb));
        be1[e] = t1; ce1[e] = 1.f - t1; cb1[e] = ce1[e] * ldany(b1, gi, isb);
        const float t2 = sigm(ldany(tau_n2, gi, isb));
        be2[e] = t2; ce2[e] = 1.f - t2; cb2[e] = ce2[e] * ldany(b2, gi, isb);
        d1[e] = 0.f; d2[e] = 0.f;
    }
    float al1[4], al2[4], m1[4], s1[4], m2[4], s2[4];
#pragma unroll
    for (int j = 0; j < 4; ++j) {
        const int n = (j < 2) ? (2 * lane + j) : (128 + 2 * lane + (j - 2));
        al1[j] = sigm(ldany(tau_m1, n, isb));
        al2[j] = sigm(ldany(tau_m2, n, isb));
        m1[j] = 0.f; s1[j] = 0.f; m2[j] = 0.f; s2[j] = 0.f;
    }
    float alr = 0.f, brv = 0.f;
    if (lane < O_) { alr = sigm(ldany(tau_mr, lane, isb)); brv = ldany(br, lane, isb); }
    float mrv = 0.f, accO = 0.f;

    __syncthreads();                     // chunk 0 ready

    for (int c = 0; c < 16; ++c) {
        const int t0 = c * 16;
        const int nst = (T_ - t0 < 16) ? (T_ - t0) : 16;

        if (w != 0) {
            if (c + 1 < 16) {            // producers: load chunk c+1
                const int t1c = (c + 1) * 16;
                const int nn  = ((T_ - t1c < 16) ? (T_ - t1c) : 16) * 128;
                const uint4* src = (const uint4*)(apb + (long)t1c * HK_);
                uint4* dst = (uint4*)ring[(c + 1) & 1];
                for (int k = tid - 64; k < nn; k += 192) dst[k] = src[k];
            }
        } else {
            const us16* rb = ring[c & 1];
            uint4 cLo = *(const uint4*)(rb + lane * 8);
            uint4 cHi = *(const uint4*)(rb + 512 + lane * 8);
            for (int q = 0; q < nst; ++q) {
                uint4 nLo = cLo, nHi = cHi;
                if (q + 1 < nst) {       // prefetch next step's row
                    nLo = *(const uint4*)(rb + (q + 1) * HK_ + lane * 8);
                    nHi = *(const uint4*)(rb + (q + 1) * HK_ + 512 + lane * 8);
                }
                const int t = t0 + q;
                float a[16];
                a[0]=bflo(cLo.x);  a[1]=bfhi(cLo.x);  a[2]=bflo(cLo.y);  a[3]=bfhi(cLo.y);
                a[4]=bflo(cLo.z);  a[5]=bfhi(cLo.z);  a[6]=bflo(cLo.w);  a[7]=bfhi(cLo.w);
                a[8]=bflo(cHi.x);  a[9]=bfhi(cHi.x);  a[10]=bflo(cHi.y); a[11]=bfhi(cHi.y);
                a[12]=bflo(cHi.z); a[13]=bfhi(cHi.z); a[14]=bflo(cHi.w); a[15]=bfhi(cHi.w);

#pragma unroll
                for (int e = 0; e < 16; ++e)
                    d1[e] = be1[e] * d1[e] + cb1[e] + ce1[e] * a[e];

                unsigned long long bal1[4];
#pragma unroll
                for (int j = 0; j < 4; ++j) {
                    const float s = (d1[j*4+0] + d1[j*4+1]) + (d1[j*4+2] + d1[j*4+3]);
                    m1[j] = m1[j] * al1[j] + (1.f - al1[j]) * s - s1[j];
                    s1[j] = (m1[j] > 1.0f) ? 1.f : 0.f;
                    bal1[j] = __ballot(s1[j] > 0.f);
                }

                if ((bal1[0] | bal1[1] | bal1[2] | bal1[3]) != 0ull) {   // rare
                    float g[16];
#pragma unroll
                    for (int e = 0; e < 16; ++e) g[e] = 0.f;
                    for (int j2 = 0; j2 < 4; ++j2) {
                        unsigned long long mm = bal1[j2];
                        while (mm) {
                            const int i = __ffsll(mm) - 1; mm &= mm - 1;
                            const int n = (j2 < 2) ? (2 * i + j2) : (128 + 2 * i + (j2 - 2));
                            const us16* wv = W2T + ((long)n << 10);
                            const uint4 wl = *(const uint4*)(wv + lane * 8);
                            const uint4 wh = *(const uint4*)(wv + 512 + lane * 8);
                            g[0]+=bflo(wl.x);  g[1]+=bfhi(wl.x);  g[2]+=bflo(wl.y);  g[3]+=bfhi(wl.y);
                            g[4]+=bflo(wl.z);  g[5]+=bfhi(wl.z);  g[6]+=bflo(wl.w);  g[7]+=bfhi(wl.w);
                            g[8]+=bflo(wh.x);  g[9]+=bfhi(wh.x);  g[10]+=bflo(wh.y); g[11]+=bfhi(wh.y);
                            g[12]+=bflo(wh.z); g[13]+=bfhi(wh.z); g[14]+=bflo(wh.w); g[15]+=bfhi(wh.w);
                        }
                    }
#pragma unroll
                    for (int e = 0; e < 16; ++e)
                        d2[e] = be2[e] * d2[e] + cb2[e] + ce2[e] * g[e];
                } else {
#pragma unroll
                    for (int e = 0; e < 16; ++e)
                        d2[e] = be2[e] * d2[e] + cb2[e];
                }

                unsigned long long bal2[4];
#pragma unroll
                for (int j = 0; j < 4; ++j) {
                    const float s = (d2[j*4+0] + d2[j*4+1]) + (d2[j*4+2] + d2[j*4+3]);
                    m2[j] = m2[j] * al2[j] + (1.f - al2[j]) * s - s2[j];
                    s2[j] = (m2[j] > 1.0f) ? 1.f : 0.f;
                    bal2[j] = __ballot(s2[j] > 0.f);
                }

                if (lane < O_) {
                    float sum = brv;
                    if ((bal2[0] | bal2[1] | bal2[2] | bal2[3]) != 0ull) {
                        for (int j2 = 0; j2 < 4; ++j2) {
                            unsigned long long mm = bal2[j2];
                            while (mm) {
                                const int i = __ffsll(mm) - 1; mm &= mm - 1;
                                const int n = (j2 < 2) ? (2 * i + j2) : (128 + 2 * i + (j2 - 2));
                                sum += ldany(Wr, (long)lane * H_ + n, isb);
                            }
                        }
                    }
                    mrv = alr * mrv + (1.f - alr) * sum;
                    if (t >= wu) accO += mrv;
                }
                cLo = nLo; cHi = nHi;
            }
        }
        __syncthreads();
    }

    if (w == 0 && lane < O_) {
        const float res = accO / (float)(T_ - wu);
        if (isb) ((us16*)out)[b * O_ + lane] = f2bfu(res);
        else     ((float*)out)[b * O_ + lane] = res;
    }
}

// ===========================================================================
// Tier-1 fallback: round-8 proven pair (fp32-direct GEMM + 1-wave recurrence)
// ===========================================================================
#define GA_LOAD(S, AV, BV) do {                                               \
    const int k0_ = (S) * 32 + half16;                                        \
    if (k0_ + 16 <= IN_) {                                                    \
        if (isb) {                                                            \
            const us16* pa_ = (const us16*)X  + arow + k0_;                   \
            const us16* pb_ = (const us16*)W1 + brow + k0_;                   \
            uint2 a0_ = *(const uint2*)pa_,        a1_ = *(const uint2*)(pa_ + 4);  \
            uint2 a2_ = *(const uint2*)(pa_ + 8),  a3_ = *(const uint2*)(pa_ + 12); \
            uint2 b0_ = *(const uint2*)pb_,        b1_ = *(const uint2*)(pb_ + 4);  \
            uint2 b2_ = *(const uint2*)(pb_ + 8),  b3_ = *(const uint2*)(pb_ + 12); \
            AV[0]=a0_.x; AV[1]=a0_.y; AV[2]=a1_.x; AV[3]=a1_.y;               \
            AV[4]=a2_.x; AV[5]=a2_.y; AV[6]=a3_.x; AV[7]=a3_.y;               \
            BV[0]=b0_.x; BV[1]=b0_.y; BV[2]=b1_.x; BV[3]=b1_.y;               \
            BV[4]=b2_.x; BV[5]=b2_.y; BV[6]=b3_.x; BV[7]=b3_.y;               \
        } else {                                                              \
            const float* pa_ = (const float*)X  + arow + k0_;                 \
            const float* pb_ = (const float*)W1 + brow + k0_;                 \
            float4 fa0_ = *(const float4*)pa_,        fa1_ = *(const float4*)(pa_ + 4);  \
            float4 fa2_ = *(const float4*)(pa_ + 8),  fa3_ = *(const float4*)(pa_ + 12); \
            float4 fb0_ = *(const float4*)pb_,        fb1_ = *(const float4*)(pb_ + 4);  \
            float4 fb2_ = *(const float4*)(pb_ + 8),  fb3_ = *(const float4*)(pb_ + 12); \
            AV[0] = (unsigned)f2bfu(fa0_.x) | ((unsigned)f2bfu(fa0_.y) << 16); \
            AV[1] = (unsigned)f2bfu(fa0_.z) | ((unsigned)f2bfu(fa0_.w) << 16); \
            AV[2] = (unsigned)f2bfu(fa1_.x) | ((unsigned)f2bfu(fa1_.y) << 16); \
            AV[3] = (unsigned)f2bfu(fa1_.z) | ((unsigned)f2bfu(fa1_.w) << 16); \
            AV[4] = (unsigned)f2bfu(fa2_.x) | ((unsigned)f2bfu(fa2_.y) << 16); \
            AV[5] = (unsigned)f2bfu(fa2_.z) | ((unsigned)f2bfu(fa2_.w) << 16); \
            AV[6] = (unsigned)f2bfu(fa3_.x) | ((unsigned)f2bfu(fa3_.y) << 16); \
            AV[7] = (unsigned)f2bfu(fa3_.z) | ((unsigned)f2bfu(fa3_.w) << 16); \
            BV[0] = (unsigned)f2bfu(fb0_.x) | ((unsigned)f2bfu(fb0_.y) << 16); \
            BV[1] = (unsigned)f2bfu(fb0_.z) | ((unsigned)f2bfu(fb0_.w) << 16); \
            BV[2] = (unsigned)f2bfu(fb1_.x) | ((unsigned)f2bfu(fb1_.y) << 16); \
            BV[3] = (unsigned)f2bfu(fb1_.z) | ((unsigned)f2bfu(fb1_.w) << 16); \
            BV[4] = (unsigned)f2bfu(fb2_.x) | ((unsigned)f2bfu(fb2_.y) << 16); \
            BV[5] = (unsigned)f2bfu(fb2_.z) | ((unsigned)f2bfu(fb2_.w) << 16); \
            BV[6] = (unsigned)f2bfu(fb3_.x) | ((unsigned)f2bfu(fb3_.y) << 16); \
            BV[7] = (unsigned)f2bfu(fb3_.z) | ((unsigned)f2bfu(fb3_.w) << 16); \
        }                                                                     \
    } else {                                                                  \
        _Pragma("unroll")                                                     \
        for (int e_ = 0; e_ < 8; ++e_) { AV[e_] = 0u; BV[e_] = 0u; }          \
        _Pragma("unroll")                                                     \
        for (int e_ = 0; e_ < 16; ++e_) {                                     \
            int k_ = k0_ + e_;                                                \
            if (k_ < IN_) {                                                   \
                unsigned va_ = (unsigned)f2bfu(ldany(X,  arow + k_, isb));    \
                unsigned vb_ = (unsigned)f2bfu(ldany(W1, brow + k_, isb));    \
                AV[e_ >> 1] |= va_ << ((e_ & 1) * 16);                        \
                BV[e_ >> 1] |= vb_ << ((e_ & 1) * 16);                        \
            }                                                                 \
        }                                                                     \
    }                                                                         \
} while (0)

#define GA_STORE(AV, BV) do {                                                 \
    uint4 u0_; u0_.x = AV[0]; u0_.y = AV[1]; u0_.z = AV[2]; u0_.w = AV[3];    \
    uint4 u1_; u1_.x = AV[4]; u1_.y = AV[5]; u1_.z = AV[6]; u1_.w = AV[7];    \
    uint4 v0_; v0_.x = BV[0]; v0_.y = BV[1]; v0_.z = BV[2]; v0_.w = BV[3];    \
    uint4 v1_; v1_.x = BV[4]; v1_.y = BV[5]; v1_.z = BV[6]; v1_.w = BV[7];    \
    *(uint4*)asw       = u0_; *(uint4*)(asw + 8) = u1_;                       \
    *(uint4*)bsw       = v0_; *(uint4*)(bsw + 8) = v1_;                       \
} while (0)

#define GA_MFMA() do {                                                        \
    short8 af_[4], bf_[4];                                                    \
    _Pragma("unroll")                                                         \
    for (int i_ = 0; i_ < 4; ++i_) af_[i_] = *(const short8*)(As + aoff[i_]); \
    _Pragma("unroll")                                                         \
    for (int j_ = 0; j_ < 4; ++j_) bf_[j_] = *(const short8*)(Bs + boff[j_]); \
    _Pragma("unroll")                                                         \
    for (int i_ = 0; i_ < 4; ++i_)                                            \
        _Pragma("unroll")                                                     \
        for (int j_ = 0; j_ < 4; ++j_)                                        \
            acc[i_][j_] = __builtin_amdgcn_mfma_f32_16x16x32_bf16(            \
                af_[i_], bf_[j_], acc[i_][j_], 0, 0, 0);                      \
} while (0)

__global__ __launch_bounds__(256) void gemm_apre(
    const void* __restrict__ X, const void* __restrict__ W1,
    const us16* __restrict__ taun, us16* __restrict__ Apre)
{
    const bool isb = detect_bf16(taun);
    __shared__ __align__(16) us16 As[128 * LDP_];
    __shared__ __align__(16) us16 Bs[128 * LDP_];

    const int L  = blockIdx.x;
    const int mt = (L & 7) + ((L >> 6) << 3);
    const int nt = (L >> 3) & 7;
    if (mt >= NPAIR_ / 128) return;
    const int m0 = mt * 128, n0 = nt * 128;

    const int tid  = threadIdx.x;
    const int lane = tid & 63;
    const int w    = tid >> 6;
    const int wr   = w >> 1, wc = w & 1;
    const int l16  = lane & 15, quad = lane >> 4;
    const int ra   = tid >> 1;
    const int half16 = (tid & 1) * 16;

    f32x4 acc[4][4];
#pragma unroll
    for (int i = 0; i < 4; ++i)
#pragma unroll
        for (int j = 0; j < 4; ++j) acc[i][j] = (f32x4){0.f, 0.f, 0.f, 0.f};

    int aoff[4], boff[4];
#pragma unroll
    for (int i = 0; i < 4; ++i) {
        aoff[i] = (wr * 64 + i * 16 + l16) * LDP_ + quad * 8;
        boff[i] = (wc * 64 + i * 16 + l16) * LDP_ + quad * 8;
    }

    const long arow = (long)(m0 + ra) * IN_;
    const long brow = (long)(n0 + ra) * IN_;
    us16* asw = As + ra * LDP_ + half16;
    us16* bsw = Bs + ra * LDP_ + half16;

    unsigned av0[8], bv0[8], av1[8], bv1[8];
    GA_LOAD(0, av0, bv0);

    for (int ss = 0; ss < 11; ++ss) {
        __syncthreads();
        GA_STORE(av0, bv0);
        __syncthreads();
        GA_LOAD(2 * ss + 1, av1, bv1);
        GA_MFMA();
        __syncthreads();
        GA_STORE(av1, bv1);
        __syncthreads();
        if (ss < 10) GA_LOAD(2 * ss + 2, av0, bv0);
        GA_MFMA();
    }

#pragma unroll
    for (int i = 0; i < 4; ++i) {
#pragma unroll
        for (int j = 0; j < 4; ++j) {
            const int gm = m0 + wr * 64 + i * 16 + quad * 4;
            const int gn = n0 + wc * 64 + j * 16 + l16;
            us16* op = Apre + (long)gm * HK_ + gn;
#pragma unroll
            for (int r = 0; r < 4; ++r)
                op[(long)r * HK_] = f2bfu(acc[i][j][r]);
        }
    }
}

__global__ __launch_bounds__(64) void dhsfnn_wave(
    const us16* __restrict__ Apre,
    const void* __restrict__ b1,  const void* __restrict__ tau_n1,
    const void* __restrict__ tau_m1,
    const void* __restrict__ b2,  const void* __restrict__ tau_n2,
    const void* __restrict__ tau_m2,
    const void* __restrict__ Wr,  const void* __restrict__ br,
    const void* __restrict__ tau_mr,
    const us16* __restrict__ W2T,
    const int* __restrict__ warmup_p,
    void* __restrict__ out)
{
    const int lane = threadIdx.x;
    const int b    = blockIdx.x;
    const bool isb = detect_bf16((const us16*)tau_n1);
    const int wu   = *warmup_p;

    float be1[16], cb1[16], be2[16], cb2[16], d1[16], d2[16];
#pragma unroll
    for (int e = 0; e < 16; ++e) {
        const long gi = (long)lane * 16 + e;
        const float t1 = sigm(ldany(tau_n1, gi, isb));
        be1[e] = t1; cb1[e] = (1.f - t1) * ldany(b1, gi, isb);
        const float t2 = sigm(ldany(tau_n2, gi, isb));
        be2[e] = t2; cb2[e] = (1.f - t2) * ldany(b2, gi, isb);
        d1[e] = 0.f; d2[e] = 0.f;
    }
    float al1[4], al2[4], m1[4], s1[4], m2[4], s2[4];
#pragma unroll
    for (int j = 0; j < 4; ++j) {
        al1[j] = sigm(ldany(tau_m1, lane * 4 + j, isb));
        al2[j] = sigm(ldany(tau_m2, lane * 4 + j, isb));
        m1[j] = 0.f; s1[j] = 0.f; m2[j] = 0.f; s2[j] = 0.f;
    }
    float alr = 0.f, brv = 0.f;
    if (lane < O_) { alr = sigm(ldany(tau_mr, lane, isb)); brv = ldany(br, lane, isb); }
    float mrv = 0.f, accO = 0.f;

    const us16* ap = Apre + (long)b * T_ * HK_ + lane * 16;

    auto wstep = [&](int t, uint4 lo, uint4 hi) {
        float a[16];
        a[0]=bflo(lo.x);  a[1]=bfhi(lo.x);  a[2]=bflo(lo.y);  a[3]=bfhi(lo.y);
        a[4]=bflo(lo.z);  a[5]=bfhi(lo.z);  a[6]=bflo(lo.w);  a[7]=bfhi(lo.w);
        a[8]=bflo(hi.x);  a[9]=bfhi(hi.x);  a[10]=bflo(hi.y); a[11]=bfhi(hi.y);
        a[12]=bflo(hi.z); a[13]=bfhi(hi.z); a[14]=bflo(hi.w); a[15]=bfhi(hi.w);
#pragma unroll
        for (int e = 0; e < 16; ++e)
            d1[e] = be1[e] * d1[e] + cb1[e] + (1.f - be1[e]) * a[e];
        unsigned long long bal1[4];
#pragma unroll
        for (int j = 0; j < 4; ++j) {
            const float s = (d1[j*4+0] + d1[j*4+1]) + (d1[j*4+2] + d1[j*4+3]);
            m1[j] = m1[j] * al1[j] + (1.f - al1[j]) * s - s1[j];
            s1[j] = (m1[j] > 1.0f) ? 1.f : 0.f;
            bal1[j] = __ballot(s1[j] > 0.f);
        }
        if ((bal1[0] | bal1[1] | bal1[2] | bal1[3]) != 0ull) {
            float g[16];
#pragma unroll
            for (int e = 0; e < 16; ++e) g[e] = 0.f;
            for (int j2 = 0; j2 < 4; ++j2) {
                unsigned long long mm = bal1[j2];
                while (mm) {
                    const int i = __ffsll(mm) - 1; mm &= mm - 1;
                    const us16* wv = W2T + ((long)(i * 4 + j2) << 10) + lane * 16;
                    const uint4 wl = *(const uint4*)wv;
                    const uint4 wh = *(const uint4*)(wv + 8);
                    g[0]+=bflo(wl.x);  g[1]+=bfhi(wl.x);  g[2]+=bflo(wl.y);  g[3]+=bfhi(wl.y);
                    g[4]+=bflo(wl.z);  g[5]+=bfhi(wl.z);  g[6]+=bflo(wl.w);  g[7]+=bfhi(wl.w);
                    g[8]+=bflo(wh.x);  g[9]+=bfhi(wh.x);  g[10]+=bflo(wh.y); g[11]+=bfhi(wh.y);
                    g[12]+=bflo(wh.z); g[13]+=bfhi(wh.z); g[14]+=bflo(wh.w); g[15]+=bfhi(wh.w);
                }
            }
#pragma unroll
            for (int e = 0; e < 16; ++e)
                d2[e] = be2[e] * d2[e] + cb2[e] + (1.f - be2[e]) * g[e];
        } else {
#pragma unroll
            for (int e = 0; e < 16; ++e)
                d2[e] = be2[e] * d2[e] + cb2[e];
        }
        unsigned long long bal2[4];
#pragma unroll
        for (int j = 0; j < 4; ++j) {
            const float s = (d2[j*4+0] + d2[j*4+1]) + (d2[j*4+2] + d2[j*4+3]);
            m2[j] = m2[j] * al2[j] + (1.f - al2[j]) * s - s2[j];
            s2[j] = (m2[j] > 1.0f) ? 1.f : 0.f;
            bal2[j] = __ballot(s2[j] > 0.f);
        }
        if (lane < O_) {
            float sum = brv;
            if ((bal2[0] | bal2[1] | bal2[2] | bal2[3]) != 0ull) {
                for (int j2 = 0; j2 < 4; ++j2) {
                    unsigned long long mm = bal2[j2];
                    while (mm) {
                        const int i = __ffsll(mm) - 1; mm &= mm - 1;
                        sum += ldany(Wr, (long)lane * H_ + (i * 4 + j2), isb);
                    }
                }
            }
            mrv = alr * mrv + (1.f - alr) * sum;
            if (t >= wu) accO += mrv;
        }
    };

    uint4 q0a = *(const uint4*)(ap);
    uint4 q0b = *(const uint4*)(ap + 8);
    uint4 q1a = *(const uint4*)(ap + HK_);
    uint4 q1b = *(const uint4*)(ap + HK_ + 8);
    uint4 q2a = *(const uint4*)(ap + 2 * HK_);
    uint4 q2b = *(const uint4*)(ap + 2 * HK_ + 8);
    uint4 q3a = *(const uint4*)(ap + 3 * HK_);
    uint4 q3b = *(const uint4*)(ap + 3 * HK_ + 8);

    int t = 0;
    for (int it = 0; it < 62; ++it) {
        wstep(t + 0, q0a, q0b);
        q0a = *(const uint4*)(ap + (long)(t + 4) * HK_);
        q0b = *(const uint4*)(ap + (long)(t + 4) * HK_ + 8);
        wstep(t + 1, q1a, q1b);
        if (t + 5 < T_) {
            q1a = *(const uint4*)(ap + (long)(t + 5) * HK_);
            q1b = *(const uint4*)(ap + (long)(t + 5) * HK_ + 8);
        }
        wstep(t + 2, q2a, q2b);
        if (t + 6 < T_) {
            q2a = *(const uint4*)(ap + (long)(t + 6) * HK_);
            q2b = *(const uint4*)(ap + (long)(t + 6) * HK_ + 8);
        }
        wstep(t + 3, q3a, q3b);
        if (t + 7 < T_) {
            q3a = *(const uint4*)(ap + (long)(t + 7) * HK_);
            q3b = *(const uint4*)(ap + (long)(t + 7) * HK_ + 8);
        }
        t += 4;
    }
    wstep(248, q0a, q0b);
    wstep(249, q1a, q1b);

    if (lane < O_) {
        const float res = accO / (float)(T_ - wu);
        if (isb) ((us16*)out)[b * O_ + lane] = f2bfu(res);
        else     ((float*)out)[b * O_ + lane] = res;
    }
}

// ---------------------------------------------------------------------------
// Tier-3 fallback: no workspace at all (round-2 proven).
// ---------------------------------------------------------------------------
__global__ __launch_bounds__(256) void dhsfnn_fb(
    const void* __restrict__ x,  const void* __restrict__ W1,
    const void* __restrict__ b1, const void* __restrict__ tau_n1,
    const void* __restrict__ tau_m1,
    const void* __restrict__ W2, const void* __restrict__ b2,
    const void* __restrict__ tau_n2, const void* __restrict__ tau_m2,
    const void* __restrict__ Wr, const void* __restrict__ br,
    const void* __restrict__ tau_mr,
    const int* __restrict__ warmup_p,
    void* __restrict__ out)
{
    __shared__ us16 list1[1024];
    __shared__ us16 list2[256];
    __shared__ us16 list3[256];
    __shared__ int n1s, n2s, n3s;

    const int tid = threadIdx.x;
    const int b   = blockIdx.x;
    const int h   = tid;
    const bool isb = detect_bf16((const us16*)tau_n1);
    const int wu  = *warmup_p;

    const float be1_0 = sigm(ldany(tau_n1, 4 * h + 0, isb));
    const float be1_1 = sigm(ldany(tau_n1, 4 * h + 1, isb));
    const float be1_2 = sigm(ldany(tau_n1, 4 * h + 2, isb));
    const float be1_3 = sigm(ldany(tau_n1, 4 * h + 3, isb));
    const float bi1_0 = ldany(b1, 4 * h + 0, isb), bi1_1 = ldany(b1, 4 * h + 1, isb);
    const float bi1_2 = ldany(b1, 4 * h + 2, isb), bi1_3 = ldany(b1, 4 * h + 3, isb);
    const float al1 = sigm(ldany(tau_m1, h, isb));
    const float be2_0 = sigm(ldany(tau_n2, 4 * h + 0, isb));
    const float be2_1 = sigm(ldany(tau_n2, 4 * h + 1, isb));
    const float be2_2 = sigm(ldany(tau_n2, 4 * h + 2, isb));
    const float be2_3 = sigm(ldany(tau_n2, 4 * h + 3, isb));
    const float bi2_0 = ldany(b2, 4 * h + 0, isb), bi2_1 = ldany(b2, 4 * h + 1, isb);
    const float bi2_2 = ldany(b2, 4 * h + 2, isb), bi2_3 = ldany(b2, 4 * h + 3, isb);
    const float al2 = sigm(ldany(tau_m2, h, isb));
    float alr = 0.f, brv = 0.f;
    if (h < O_) { alr = sigm(ldany(tau_mr, h, isb)); brv = ldany(br, h, isb); }

    float d1_0 = 0.f, d1_1 = 0.f, d1_2 = 0.f, d1_3 = 0.f, m1v = 0.f, s1f = 0.f;
    float d2_0 = 0.f, d2_1 = 0.f, d2_2 = 0.f, d2_3 = 0.f, m2v = 0.f, s2f = 0.f;
    float mrv = 0.f, accO = 0.f;

    const long xbase = (long)b * T_ * IN_;
    float xv0 = ldany(x, xbase + tid, isb);
    float xv1 = ldany(x, xbase + tid + 256, isb);
    float xv2 = (tid + 512 < IN_) ? ldany(x, xbase + tid + 512, isb) : 0.f;

    for (int t = 0; t < T_; ++t) {
        const bool p0 = xv0 != 0.f, p1 = xv1 != 0.f, p2 = xv2 != 0.f;
        if (t + 1 < T_) {
            const long nbx = xbase + (long)(t + 1) * IN_;
            xv0 = ldany(x, nbx + tid, isb);
            xv1 = ldany(x, nbx + tid + 256, isb);
            xv2 = (tid + 512 < IN_) ? ldany(x, nbx + tid + 512, isb) : 0.f;
        }
        __syncthreads();
        if (tid == 0) { n1s = 0; n2s = 0; n3s = 0; }
        __syncthreads();
        if (p0) { int p = atomicAdd(&n1s, 1); list1[p & 1023] = (us16)tid; }
        if (p1) { int p = atomicAdd(&n1s, 1); list1[p & 1023] = (us16)(tid + 256); }
        if (p2) { int p = atomicAdd(&n1s, 1); list1[p & 1023] = (us16)(tid + 512); }
        __syncthreads();
        int n1 = n1s; n1 = (n1 < 1024) ? n1 : 1024;

        float a0 = 0.f, a1 = 0.f, a2 = 0.f, a3 = 0.f;
#pragma unroll 2
        for (int idx = 0; idx < n1; ++idx) {
            int i = rfl((int)list1[idx]);
            i = (i < IN_) ? i : (IN_ - 1);
            long r = (long)(h * 4) * IN_ + i;
            a0 += ldany(W1, r, isb);
            a1 += ldany(W1, r + IN_, isb);
            a2 += ldany(W1, r + 2 * IN_, isb);
            a3 += ldany(W1, r + 3 * IN_, isb);
        }
        d1_0 = be1_0 * d1_0 + (1.f - be1_0) * (bi1_0 + a0);
        d1_1 = be1_1 * d1_1 + (1.f - be1_1) * (bi1_1 + a1);
        d1_2 = be1_2 * d1_2 + (1.f - be1_2) * (bi1_2 + a2);
        d1_3 = be1_3 * d1_3 + (1.f - be1_3) * (bi1_3 + a3);
        m1v = m1v * al1 + (1.f - al1) * (d1_0 + d1_1 + d1_2 + d1_3) - s1f;
        s1f = (m1v > 1.0f) ? 1.f : 0.f;

        if (s1f > 0.f) { int p = atomicAdd(&n2s, 1); list2[p & 255] = (us16)tid; }
        __syncthreads();
        int n2 = n2s; n2 = (n2 < 256) ? n2 : 256;

        a0 = 0.f; a1 = 0.f; a2 = 0.f; a3 = 0.f;
#pragma unroll 2
        for (int idx = 0; idx < n2; ++idx) {
            int i = rfl((int)list2[idx]);
            i = (i < H_) ? i : (H_ - 1);
            long r = (long)(h * 4) * H_ + i;
            a0 += ldany(W2, r, isb);
            a1 += ldany(W2, r + H_, isb);
            a2 += ldany(W2, r + 2 * H_, isb);
            a3 += ldany(W2, r + 3 * H_, isb);
        }
        d2_0 = be2_0 * d2_0 + (1.f - be2_0) * (bi2_0 + a0);
        d2_1 = be2_1 * d2_1 + (1.f - be2_1) * (bi2_1 + a1);
        d2_2 = be2_2 * d2_2 + (1.f - be2_2) * (bi2_2 + a2);
        d2_3 = be2_3 * d2_3 + (1.f - be2_3) * (bi2_3 + a3);
        m2v = m2v * al2 + (1.f - al2) * (d2_0 + d2_1 + d2_2 + d2_3) - s2f;
        s2f = (m2v > 1.0f) ? 1.f : 0.f;

        if (s2f > 0.f) { int p = atomicAdd(&n3s, 1); list3[p & 255] = (us16)tid; }
        __syncthreads();
        int n3 = n3s; n3 = (n3 < 256) ? n3 : 256;

        if (h < O_) {
            float sum = brv;
            for (int idx = 0; idx < n3; ++idx) {
                int j = (int)list3[idx];
                j = (j < H_) ? j : (H_ - 1);
                sum += ldany(Wr, (long)h * H_ + j, isb);
            }
            mrv = alr * mrv + (1.f - alr) * sum;
            if (t >= wu) accO += mrv;
        }
    }
    if (h < O_) {
        float res = accO / (float)(T_ - wu);
        if (isb) ((us16*)out)[b * O_ + h] = f2bfu(res);
        else     ((float*)out)[b * O_ + h] = res;
    }
}

// ---------------------------------------------------------------------------
extern "C" void kernel_launch(void* const* d_in, const int* in_sizes, int n_in,
                              void* d_out, int out_size, void* d_ws, size_t ws_size,
                              hipStream_t stream) {
    const void* x      = d_in[0];
    const void* W1     = d_in[1];
    const void* b1     = d_in[2];
    const void* tau_n1 = d_in[3];
    const void* tau_m1 = d_in[4];
    const void* W2     = d_in[5];
    const void* b2     = d_in[6];
    const void* tau_n2 = d_in[7];
    const void* tau_m2 = d_in[8];
    const void* Wr     = d_in[9];
    const void* br     = d_in[10];
    const void* tau_mr = d_in[11];
    const int*  warmup = (const int*)d_in[12];

    const size_t w2t_bytes  = (size_t)H_ * HK_ * 2;            //     524,288
    const size_t xbf_bytes  = (size_t)NPAIR_ * KP_ * 2;        //  90,112,000
    const size_t w1b_bytes  = (size_t)HK_ * KP_ * 2;           //   1,441,792
    const size_t apre_bytes = (size_t)NPAIR_ * HK_ * 2;        // 131,072,000

    const bool tier0 = (d_ws != nullptr &&
                        ws_size >= w2t_bytes + xbf_bytes + w1b_bytes + apre_bytes);
    const bool tier1 = (d_ws != nullptr && ws_size >= w2t_bytes + apre_bytes);

    dim3 blk(32, 8);
    if (tier0) {
        us16* W2T  = (us16*)d_ws;
        us16* Xbf  = (us16*)((char*)d_ws + w2t_bytes);
        us16* W1bf = (us16*)((char*)d_ws + w2t_bytes + xbf_bytes);
        us16* Apre = (us16*)((char*)d_ws + w2t_bytes + xbf_bytes + w1b_bytes);
        cvt_rows2<<<(NPAIR_ + HK_) / 4, 256, 0, stream>>>(
            x, W1, Xbf, W1bf, (const us16*)tau_n1);
        transpose_to_bf16<<<dim3((H_ + 31) / 32, (HK_ + 31) / 32), blk, 0, stream>>>(
            W2, W2T, HK_, H_, (const us16*)tau_n1);
        gemm_bf<<<4096, 256, 0, stream>>>(Xbf, W1bf, Apre);
        dhsfnn_pc<<<B_, 256, 0, stream>>>(
            Apre, b1, tau_n1, tau_m1, b2, tau_n2, tau_m2,
            Wr, br, tau_mr, W2T, warmup, d_out);
    } else if (tier1) {
        us16* W2T  = (us16*)d_ws;
        us16* Apre = (us16*)((char*)d_ws + w2t_bytes);
        transpose_to_bf16<<<dim3((H_ + 31) / 32, (HK_ + 31) / 32), blk, 0, stream>>>(
            W2, W2T, HK_, H_, (const us16*)tau_n1);
        gemm_apre<<<4096, 256, 0, stream>>>(x, W1, (const us16*)tau_n1, Apre);
        dhsfnn_wave<<<B_, 64, 0, stream>>>(
            Apre, b1, tau_n1, tau_m1, b2, tau_n2, tau_m2,
            Wr, br, tau_mr, W2T, warmup, d_out);
    } else {
        dhsfnn_fb<<<B_, 256, 0, stream>>>(x, W1, b1, tau_n1, tau_m1,
                                          W2, b2, tau_n2, tau_m2,
                                          Wr, br, tau_mr, warmup, d_out);
    }
}

// Round 14
// 462.213 us; speedup vs baseline: 1.1960x; 1.0398x over previous
//
#include <hip/hip_runtime.h>
#include <hip/hip_bf16.h>

typedef unsigned short us16;
typedef unsigned int u32;

#define B_   256
#define T_   250
#define IN_  700
#define KP_  704           // K padded
#define H_   256
#define O_   20
#define HK_  1024
#define NPAIR_ (B_ * T_)   // 64000
#define LDP_ 40            // tier-1 LDS pitch
#define CP_  132           // epilogue C-tile pitch (elems)

typedef __attribute__((ext_vector_type(8))) short short8;
typedef __attribute__((ext_vector_type(4))) float f32x4;

__device__ __forceinline__ float bfbits(unsigned int lo16) {
    union { unsigned int i; float f; } v; v.i = lo16 << 16; return v.f;
}
__device__ __forceinline__ float bflo(unsigned int u) {
    union { unsigned int i; float f; } v; v.i = u << 16; return v.f;
}
__device__ __forceinline__ float bfhi(unsigned int u) {
    union { unsigned int i; float f; } v; v.i = u & 0xffff0000u; return v.f;
}
__device__ __forceinline__ us16 f2bfu(float f) {
    __hip_bfloat16 h = __float2bfloat16(f);
    union { __hip_bfloat16 h; us16 u; } c; c.h = h; return c.u;
}
__device__ __forceinline__ float sigm(float x) { return 1.0f / (1.0f + expf(-x)); }
__device__ __forceinline__ int rfl(int v) { return __builtin_amdgcn_readfirstlane(v); }

// tau_n1 uniform in [2,6): bf16 => every value ushort has high byte 0x40.
// (Round-5 counters proved this dataset is fp32.)
__device__ __forceinline__ bool detect_bf16(const us16* __restrict__ taun) {
    int ok = 0;
#pragma unroll
    for (int i = 0; i < 8; i += 2) ok += ((taun[i] >> 8) == 0x40) ? 1 : 0;
    return ok == 4;
}
__device__ __forceinline__ float ldany(const void* __restrict__ p, long i, bool isb) {
    return isb ? bfbits(((const us16*)p)[i]) : ((const float*)p)[i];
}

// async global->LDS, 16B per lane; lds base must be wave-uniform.
__device__ __forceinline__ void async_cp16(const us16* g, us16* l) {
    __builtin_amdgcn_global_load_lds(
        (const __attribute__((address_space(1))) u32*)g,
        (__attribute__((address_space(3))) u32*)l, 16, 0, 0);
}

// ---------------------------------------------------------------------------
// Merged row convert+pad for X and W1 (one launch): [*,700] -> [*,704] bf16.
// One wave per row; float4 loads + uint2 stores (700 = 175x4; chunk 175 = pad).
// ---------------------------------------------------------------------------
__global__ __launch_bounds__(256) void cvt_rows2(
    const void* __restrict__ xin, const void* __restrict__ w1in,
    us16* __restrict__ xout, us16* __restrict__ w1out,
    const us16* __restrict__ taun) {
    const bool isb = detect_bf16(taun);
    const int r = blockIdx.x * 4 + (threadIdx.x >> 6);
    const int l = threadIdx.x & 63;
    const void* in; us16* out; long ibase, obase;
    if (r < NPAIR_) {
        in = xin;  out = xout;  ibase = (long)r * IN_; obase = (long)r * KP_;
    } else {
        const int r2 = r - NPAIR_;
        if (r2 >= HK_) return;
        in = w1in; out = w1out; ibase = (long)r2 * IN_; obase = (long)r2 * KP_;
    }
    for (int c = l; c < 176; c += 64) {
        uint2 o;
        if (c < 175) {
            if (isb) {
                o = *(const uint2*)((const us16*)in + ibase + 4 * c);
            } else {
                float4 f = *(const float4*)((const float*)in + ibase + 4 * c);
                o.x = (u32)f2bfu(f.x) | ((u32)f2bfu(f.y) << 16);
                o.y = (u32)f2bfu(f.z) | ((u32)f2bfu(f.w) << 16);
            }
        } else { o.x = 0u; o.y = 0u; }
        *(uint2*)(out + obase + 4 * c) = o;
    }
}

// ---------------------------------------------------------------------------
__global__ void transpose_to_bf16(const void* __restrict__ in, us16* __restrict__ out,
                                  int R, int C, const us16* __restrict__ taun) {
    const bool isb = detect_bf16(taun);
    __shared__ us16 tile[32][33];
    int c0 = blockIdx.x * 32, r0 = blockIdx.y * 32;
    int tx = threadIdx.x, ty = threadIdx.y;   // block (32,8)
#pragma unroll
    for (int j = 0; j < 32; j += 8) {
        int r = r0 + ty + j, c = c0 + tx;
        if (r < R && c < C) tile[ty + j][tx] = f2bfu(ldany(in, (long)r * C + c, isb));
    }
    __syncthreads();
#pragma unroll
    for (int j = 0; j < 32; j += 8) {
        int c = c0 + ty + j, r = r0 + tx;
        if (c < C && r < R) out[(long)c * R + r] = tile[tx][ty + j];
    }
}

// ---------------------------------------------------------------------------
// Tier-0 GEMM, DOUBLE-BUFFERED LDS (one barrier/step, drain overlapped):
// Apre[64000,1024] = Xb[64000,704] · W1b[1024,704]^T, bf16, BM=128, BK=64.
// Step s issues async global_load_lds for step s+1 into the idle buffer
// BEFORE the MFMAs on the current buffer; the end-of-step barrier's vmcnt
// drain is thus overlapped by ~350 cyc of compute. The same barrier also
// frees the current buffer for step s+2's writes. XOR bank swizzle kept.
// ---------------------------------------------------------------------------
__global__ __launch_bounds__(256) void gemm_bf(
    const us16* __restrict__ Xb, const us16* __restrict__ W1b,
    us16* __restrict__ Apre)
{
    // buf0: A [0,8192) B [8192,16384); buf1: A [16384,24576) B [24576,32768)
    // epilogue reuses [0, 128*CP_) = 16896 elems
    __shared__ __align__(16) us16 smem[32768];   // 64 KB

    const int L  = blockIdx.x;
    const int mt = (L & 7) + ((L >> 6) << 3);
    const int nt = (L >> 3) & 7;
    if (mt >= NPAIR_ / 128) return;
    const int m0 = mt * 128, n0 = nt * 128;

    const int tid  = threadIdx.x;
    const int lane = tid & 63;
    const int w    = tid >> 6;
    const int wr   = w >> 1, wc = w & 1;
    const int l16  = lane & 15, quad = lane >> 4;

    // staging: lane = rr*8 + cc; stages global 16B-chunk (cc^rr) of row rr
    const int rr    = lane >> 3;
    const int ccsw  = ((lane & 7) ^ rr) * 8;         // swizzled chunk start (elems)
    const us16* xg[4]; const us16* wg[4];
    int asl[4], bsl[4];                              // LDS elem offsets (buf0)
#pragma unroll
    for (int i = 0; i < 4; ++i) {
        const int blkrow = (w * 4 + i) * 8;
        xg[i]  = Xb  + (long)(m0 + blkrow + rr) * KP_ + ccsw;
        wg[i]  = W1b + (long)(n0 + blkrow + rr) * KP_ + ccsw;
        asl[i] = (w * 4 + i) * 512;                  // wave-uniform base (1024 B)
        bsl[i] = 8192 + (w * 4 + i) * 512;
    }

    f32x4 acc[4][4];
#pragma unroll
    for (int i = 0; i < 4; ++i)
#pragma unroll
        for (int j = 0; j < 4; ++j) acc[i][j] = (f32x4){0.f, 0.f, 0.f, 0.f};

    const int sw = l16 & 7;
    int aoff0[4], aoff1[4], boff0[4], boff1[4];
#pragma unroll
    for (int i = 0; i < 4; ++i) {
        const int ar = wr * 64 + i * 16 + l16;
        const int br = wc * 64 + i * 16 + l16;
        aoff0[i] = ar * 64 + ((quad ^ sw) << 3);
        aoff1[i] = ar * 64 + (((quad + 4) ^ sw) << 3);
        boff0[i] = 8192 + br * 64 + ((quad ^ sw) << 3);
        boff1[i] = 8192 + br * 64 + (((quad + 4) ^ sw) << 3);
    }

    // prologue: stage step 0 into buf0
#pragma unroll
    for (int i = 0; i < 4; ++i) async_cp16(xg[i], smem + asl[i]);
#pragma unroll
    for (int i = 0; i < 4; ++i) async_cp16(wg[i], smem + bsl[i]);
    __syncthreads();                           // drain -> buf0 visible

    for (int s = 0; s < 11; ++s) {             // 11 * 64 = 704
        const int cur = (s & 1) * 16384;
        const int nxt = 16384 - cur;
        if (s + 1 < 11) {                      // issue s+1 loads into idle buffer
            const int kb = (s + 1) * 64;
#pragma unroll
            for (int i = 0; i < 4; ++i) async_cp16(xg[i] + kb, smem + nxt + asl[i]);
#pragma unroll
            for (int i = 0; i < 4; ++i) async_cp16(wg[i] + kb, smem + nxt + bsl[i]);
        }

        short8 af[4][2], bfv[4][2];
#pragma unroll
        for (int i = 0; i < 4; ++i) {
            af[i][0]  = *(const short8*)(smem + cur + aoff0[i]);
            af[i][1]  = *(const short8*)(smem + cur + aoff1[i]);
            bfv[i][0] = *(const short8*)(smem + cur + boff0[i]);
            bfv[i][1] = *(const short8*)(smem + cur + boff1[i]);
        }
#pragma unroll
        for (int h = 0; h < 2; ++h)
#pragma unroll
            for (int i = 0; i < 4; ++i)
#pragma unroll
                for (int j = 0; j < 4; ++j)
                    acc[i][j] = __builtin_amdgcn_mfma_f32_16x16x32_bf16(
                        af[i][h], bfv[j][h], acc[i][j], 0, 0, 0);

        __syncthreads();   // drains s+1 asyncs (flew under MFMAs); frees cur for s+2
    }

    // epilogue: stage C-tile in LDS (reuse smem[0:16896)), coalesced 256 B rows
#pragma unroll
    for (int i = 0; i < 4; ++i)
#pragma unroll
        for (int j = 0; j < 4; ++j)
#pragma unroll
            for (int r = 0; r < 4; ++r)
                smem[(wr * 64 + i * 16 + quad * 4 + r) * CP_ +
                     (wc * 64 + j * 16 + l16)] = f2bfu(acc[i][j][r]);
    __syncthreads();
    for (int r2 = 0; r2 < 32; ++r2) {
        const int row = w * 32 + r2;
        const u32 v = *(const u32*)(smem + row * CP_ + lane * 2);
        *(u32*)(Apre + (long)(m0 + row) * HK_ + n0 + lane * 2) = v;
    }
}

// ---------------------------------------------------------------------------
// Tier-0 phase 2 (round-11 proven): producer-consumer, conflict-free consumer
// reads (lane owns elems [8l,8l+8) u [512+8l,512+8l+8)), register prefetch.
// ---------------------------------------------------------------------------
__global__ __launch_bounds__(256) void dhsfnn_pc(
    const us16* __restrict__ Apre,
    const void* __restrict__ b1,  const void* __restrict__ tau_n1,
    const void* __restrict__ tau_m1,
    const void* __restrict__ b2,  const void* __restrict__ tau_n2,
    const void* __restrict__ tau_m2,
    const void* __restrict__ Wr,  const void* __restrict__ br,
    const void* __restrict__ tau_mr,
    const us16* __restrict__ W2T,      // [presyn 256][elem 1024] bf16
    const int* __restrict__ warmup_p,
    void* __restrict__ out)
{
    __shared__ __align__(16) us16 ring[2][16 * HK_];   // 2 x 32 KB

    const int tid  = threadIdx.x;
    const int lane = tid & 63;
    const int w    = tid >> 6;
    const int b    = blockIdx.x;
    const bool isb = detect_bf16((const us16*)tau_n1);
    const int wu   = *warmup_p;

    const us16* apb = Apre + (long)b * T_ * HK_;

    {   // chunk 0: all 4 waves load
        const uint4* src = (const uint4*)apb;
        uint4* dst = (uint4*)ring[0];
        for (int k = tid; k < 16 * 128; k += 256) dst[k] = src[k];
    }

    float be1[16], cb1[16], ce1[16], be2[16], cb2[16], ce2[16], d1[16], d2[16];
#pragma unroll
    for (int e = 0; e < 16; ++e) {
        const long gi = (e < 8) ? ((long)lane * 8 + e) : (512 + (long)lane * 8 + e - 8);
        const float t1 = sigm(ldany(tau_n1, gi, isb));
        be1[e] = t1; ce1[e] = 1.f - t1; cb1[e] = ce1[e] * ldany(b1, gi, isb);
        const float t2 = sigm(ldany(tau_n2, gi, isb));
        be2[e] = t2; ce2[e] = 1.f - t2; cb2[e] = ce2[e] * ldany(b2, gi, isb);
        d1[e] = 0.f; d2[e] = 0.f;
    }
    float al1[4], al2[4], m1[4], s1[4], m2[4], s2[4];
#pragma unroll
    for (int j = 0; j < 4; ++j) {
        const int n = (j < 2) ? (2 * lane + j) : (128 + 2 * lane + (j - 2));
        al1[j] = sigm(ldany(tau_m1, n, isb));
        al2[j] = sigm(ldany(tau_m2, n, isb));
        m1[j] = 0.f; s1[j] = 0.f; m2[j] = 0.f; s2[j] = 0.f;
    }
    float alr = 0.f, brv = 0.f;
    if (lane < O_) { alr = sigm(ldany(tau_mr, lane, isb)); brv = ldany(br, lane, isb); }
    float mrv = 0.f, accO = 0.f;

    __syncthreads();                     // chunk 0 ready

    for (int c = 0; c < 16; ++c) {
        const int t0 = c * 16;
        const int nst = (T_ - t0 < 16) ? (T_ - t0) : 16;

        if (w != 0) {
            if (c + 1 < 16) {            // producers: load chunk c+1
                const int t1c = (c + 1) * 16;
                const int nn  = ((T_ - t1c < 16) ? (T_ - t1c) : 16) * 128;
                const uint4* src = (const uint4*)(apb + (long)t1c * HK_);
                uint4* dst = (uint4*)ring[(c + 1) & 1];
                for (int k = tid - 64; k < nn; k += 192) dst[k] = src[k];
            }
        } else {
            const us16* rb = ring[c & 1];
            uint4 cLo = *(const uint4*)(rb + lane * 8);
            uint4 cHi = *(const uint4*)(rb + 512 + lane * 8);
            for (int q = 0; q < nst; ++q) {
                uint4 nLo = cLo, nHi = cHi;
                if (q + 1 < nst) {       // prefetch next step's row
                    nLo = *(const uint4*)(rb + (q + 1) * HK_ + lane * 8);
                    nHi = *(const uint4*)(rb + (q + 1) * HK_ + 512 + lane * 8);
                }
                const int t = t0 + q;
                float a[16];
                a[0]=bflo(cLo.x);  a[1]=bfhi(cLo.x);  a[2]=bflo(cLo.y);  a[3]=bfhi(cLo.y);
                a[4]=bflo(cLo.z);  a[5]=bfhi(cLo.z);  a[6]=bflo(cLo.w);  a[7]=bfhi(cLo.w);
                a[8]=bflo(cHi.x);  a[9]=bfhi(cHi.x);  a[10]=bflo(cHi.y); a[11]=bfhi(cHi.y);
                a[12]=bflo(cHi.z); a[13]=bfhi(cHi.z); a[14]=bflo(cHi.w); a[15]=bfhi(cHi.w);

#pragma unroll
                for (int e = 0; e < 16; ++e)
                    d1[e] = be1[e] * d1[e] + cb1[e] + ce1[e] * a[e];

                unsigned long long bal1[4];
#pragma unroll
                for (int j = 0; j < 4; ++j) {
                    const float s = (d1[j*4+0] + d1[j*4+1]) + (d1[j*4+2] + d1[j*4+3]);
                    m1[j] = m1[j] * al1[j] + (1.f - al1[j]) * s - s1[j];
                    s1[j] = (m1[j] > 1.0f) ? 1.f : 0.f;
                    bal1[j] = __ballot(s1[j] > 0.f);
                }

                if ((bal1[0] | bal1[1] | bal1[2] | bal1[3]) != 0ull) {   // rare
                    float g[16];
#pragma unroll
                    for (int e = 0; e < 16; ++e) g[e] = 0.f;
                    for (int j2 = 0; j2 < 4; ++j2) {
                        unsigned long long mm = bal1[j2];
                        while (mm) {
                            const int i = __ffsll(mm) - 1; mm &= mm - 1;
                            const int n = (j2 < 2) ? (2 * i + j2) : (128 + 2 * i + (j2 - 2));
                            const us16* wv = W2T + ((long)n << 10);
                            const uint4 wl = *(const uint4*)(wv + lane * 8);
                            const uint4 wh = *(const uint4*)(wv + 512 + lane * 8);
                            g[0]+=bflo(wl.x);  g[1]+=bfhi(wl.x);  g[2]+=bflo(wl.y);  g[3]+=bfhi(wl.y);
                            g[4]+=bflo(wl.z);  g[5]+=bfhi(wl.z);  g[6]+=bflo(wl.w);  g[7]+=bfhi(wl.w);
                            g[8]+=bflo(wh.x);  g[9]+=bfhi(wh.x);  g[10]+=bflo(wh.y); g[11]+=bfhi(wh.y);
                            g[12]+=bflo(wh.z); g[13]+=bfhi(wh.z); g[14]+=bflo(wh.w); g[15]+=bfhi(wh.w);
                        }
                    }
#pragma unroll
                    for (int e = 0; e < 16; ++e)
                        d2[e] = be2[e] * d2[e] + cb2[e] + ce2[e] * g[e];
                } else {
#pragma unroll
                    for (int e = 0; e < 16; ++e)
                        d2[e] = be2[e] * d2[e] + cb2[e];
                }

                unsigned long long bal2[4];
#pragma unroll
                for (int j = 0; j < 4; ++j) {
                    const float s = (d2[j*4+0] + d2[j*4+1]) + (d2[j*4+2] + d2[j*4+3]);
                    m2[j] = m2[j] * al2[j] + (1.f - al2[j]) * s - s2[j];
                    s2[j] = (m2[j] > 1.0f) ? 1.f : 0.f;
                    bal2[j] = __ballot(s2[j] > 0.f);
                }

                if (lane < O_) {
                    float sum = brv;
                    if ((bal2[0] | bal2[1] | bal2[2] | bal2[3]) != 0ull) {
                        for (int j2 = 0; j2 < 4; ++j2) {
                            unsigned long long mm = bal2[j2];
                            while (mm) {
                                const int i = __ffsll(mm) - 1; mm &= mm - 1;
                                const int n = (j2 < 2) ? (2 * i + j2) : (128 + 2 * i + (j2 - 2));
                                sum += ldany(Wr, (long)lane * H_ + n, isb);
                            }
                        }
                    }
                    mrv = alr * mrv + (1.f - alr) * sum;
                    if (t >= wu) accO += mrv;
                }
                cLo = nLo; cHi = nHi;
            }
        }
        __syncthreads();
    }

    if (w == 0 && lane < O_) {
        const float res = accO / (float)(T_ - wu);
        if (isb) ((us16*)out)[b * O_ + lane] = f2bfu(res);
        else     ((float*)out)[b * O_ + lane] = res;
    }
}

// ===========================================================================
// Tier-1 fallback: round-8 proven pair (fp32-direct GEMM + 1-wave recurrence)
// ===========================================================================
#define GA_LOAD(S, AV, BV) do {                                               \
    const int k0_ = (S) * 32 + half16;                                        \
    if (k0_ + 16 <= IN_) {                                                    \
        if (isb) {                                                            \
            const us16* pa_ = (const us16*)X  + arow + k0_;                   \
            const us16* pb_ = (const us16*)W1 + brow + k0_;                   \
            uint2 a0_ = *(const uint2*)pa_,        a1_ = *(const uint2*)(pa_ + 4);  \
            uint2 a2_ = *(const uint2*)(pa_ + 8),  a3_ = *(const uint2*)(pa_ + 12); \
            uint2 b0_ = *(const uint2*)pb_,        b1_ = *(const uint2*)(pb_ + 4);  \
            uint2 b2_ = *(const uint2*)(pb_ + 8),  b3_ = *(const uint2*)(pb_ + 12); \
            AV[0]=a0_.x; AV[1]=a0_.y; AV[2]=a1_.x; AV[3]=a1_.y;               \
            AV[4]=a2_.x; AV[5]=a2_.y; AV[6]=a3_.x; AV[7]=a3_.y;               \
            BV[0]=b0_.x; BV[1]=b0_.y; BV[2]=b1_.x; BV[3]=b1_.y;               \
            BV[4]=b2_.x; BV[5]=b2_.y; BV[6]=b3_.x; BV[7]=b3_.y;               \
        } else {                                                              \
            const float* pa_ = (const float*)X  + arow + k0_;                 \
            const float* pb_ = (const float*)W1 + brow + k0_;                 \
            float4 fa0_ = *(const float4*)pa_,        fa1_ = *(const float4*)(pa_ + 4);  \
            float4 fa2_ = *(const float4*)(pa_ + 8),  fa3_ = *(const float4*)(pa_ + 12); \
            float4 fb0_ = *(const float4*)pb_,        fb1_ = *(const float4*)(pb_ + 4);  \
            float4 fb2_ = *(const float4*)(pb_ + 8),  fb3_ = *(const float4*)(pb_ + 12); \
            AV[0] = (unsigned)f2bfu(fa0_.x) | ((unsigned)f2bfu(fa0_.y) << 16); \
            AV[1] = (unsigned)f2bfu(fa0_.z) | ((unsigned)f2bfu(fa0_.w) << 16); \
            AV[2] = (unsigned)f2bfu(fa1_.x) | ((unsigned)f2bfu(fa1_.y) << 16); \
            AV[3] = (unsigned)f2bfu(fa1_.z) | ((unsigned)f2bfu(fa1_.w) << 16); \
            AV[4] = (unsigned)f2bfu(fa2_.x) | ((unsigned)f2bfu(fa2_.y) << 16); \
            AV[5] = (unsigned)f2bfu(fa2_.z) | ((unsigned)f2bfu(fa2_.w) << 16); \
            AV[6] = (unsigned)f2bfu(fa3_.x) | ((unsigned)f2bfu(fa3_.y) << 16); \
            AV[7] = (unsigned)f2bfu(fa3_.z) | ((unsigned)f2bfu(fa3_.w) << 16); \
            BV[0] = (unsigned)f2bfu(fb0_.x) | ((unsigned)f2bfu(fb0_.y) << 16); \
            BV[1] = (unsigned)f2bfu(fb0_.z) | ((unsigned)f2bfu(fb0_.w) << 16); \
            BV[2] = (unsigned)f2bfu(fb1_.x) | ((unsigned)f2bfu(fb1_.y) << 16); \
            BV[3] = (unsigned)f2bfu(fb1_.z) | ((unsigned)f2bfu(fb1_.w) << 16); \
            BV[4] = (unsigned)f2bfu(fb2_.x) | ((unsigned)f2bfu(fb2_.y) << 16); \
            BV[5] = (unsigned)f2bfu(fb2_.z) | ((unsigned)f2bfu(fb2_.w) << 16); \
            BV[6] = (unsigned)f2bfu(fb3_.x) | ((unsigned)f2bfu(fb3_.y) << 16); \
            BV[7] = (unsigned)f2bfu(fb3_.z) | ((unsigned)f2bfu(fb3_.w) << 16); \
        }                                                                     \
    } else {                                                                  \
        _Pragma("unroll")                                                     \
        for (int e_ = 0; e_ < 8; ++e_) { AV[e_] = 0u; BV[e_] = 0u; }          \
        _Pragma("unroll")                                                     \
        for (int e_ = 0; e_ < 16; ++e_) {                                     \
            int k_ = k0_ + e_;                                                \
            if (k_ < IN_) {                                                   \
                unsigned va_ = (unsigned)f2bfu(ldany(X,  arow + k_, isb));    \
                unsigned vb_ = (unsigned)f2bfu(ldany(W1, brow + k_, isb));    \
                AV[e_ >> 1] |= va_ << ((e_ & 1) * 16);                        \
                BV[e_ >> 1] |= vb_ << ((e_ & 1) * 16);                        \
            }                                                                 \
        }                                                                     \
    }                                                                         \
} while (0)

#define GA_STORE(AV, BV) do {                                                 \
    uint4 u0_; u0_.x = AV[0]; u0_.y = AV[1]; u0_.z = AV[2]; u0_.w = AV[3];    \
    uint4 u1_; u1_.x = AV[4]; u1_.y = AV[5]; u1_.z = AV[6]; u1_.w = AV[7];    \
    uint4 v0_; v0_.x = BV[0]; v0_.y = BV[1]; v0_.z = BV[2]; v0_.w = BV[3];    \
    uint4 v1_; v1_.x = BV[4]; v1_.y = BV[5]; v1_.z = BV[6]; v1_.w = BV[7];    \
    *(uint4*)asw       = u0_; *(uint4*)(asw + 8) = u1_;                       \
    *(uint4*)bsw       = v0_; *(uint4*)(bsw + 8) = v1_;                       \
} while (0)

#define GA_MFMA() do {                                                        \
    short8 af_[4], bf_[4];                                                    \
    _Pragma("unroll")                                                         \
    for (int i_ = 0; i_ < 4; ++i_) af_[i_] = *(const short8*)(As + aoff[i_]); \
    _Pragma("unroll")                                                         \
    for (int j_ = 0; j_ < 4; ++j_) bf_[j_] = *(const short8*)(Bs + boff[j_]); \
    _Pragma("unroll")                                                         \
    for (int i_ = 0; i_ < 4; ++i_)                                            \
        _Pragma("unroll")                                                     \
        for (int j_ = 0; j_ < 4; ++j_)                                        \
            acc[i_][j_] = __builtin_amdgcn_mfma_f32_16x16x32_bf16(            \
                af_[i_], bf_[j_], acc[i_][j_], 0, 0, 0);                      \
} while (0)

__global__ __launch_bounds__(256) void gemm_apre(
    const void* __restrict__ X, const void* __restrict__ W1,
    const us16* __restrict__ taun, us16* __restrict__ Apre)
{
    const bool isb = detect_bf16(taun);
    __shared__ __align__(16) us16 As[128 * LDP_];
    __shared__ __align__(16) us16 Bs[128 * LDP_];

    const int L  = blockIdx.x;
    const int mt = (L & 7) + ((L >> 6) << 3);
    const int nt = (L >> 3) & 7;
    if (mt >= NPAIR_ / 128) return;
    const int m0 = mt * 128, n0 = nt * 128;

    const int tid  = threadIdx.x;
    const int lane = tid & 63;
    const int w    = tid >> 6;
    const int wr   = w >> 1, wc = w & 1;
    const int l16  = lane & 15, quad = lane >> 4;
    const int ra   = tid >> 1;
    const int half16 = (tid & 1) * 16;

    f32x4 acc[4][4];
#pragma unroll
    for (int i = 0; i < 4; ++i)
#pragma unroll
        for (int j = 0; j < 4; ++j) acc[i][j] = (f32x4){0.f, 0.f, 0.f, 0.f};

    int aoff[4], boff[4];
#pragma unroll
    for (int i = 0; i < 4; ++i) {
        aoff[i] = (wr * 64 + i * 16 + l16) * LDP_ + quad * 8;
        boff[i] = (wc * 64 + i * 16 + l16) * LDP_ + quad * 8;
    }

    const long arow = (long)(m0 + ra) * IN_;
    const long brow = (long)(n0 + ra) * IN_;
    us16* asw = As + ra * LDP_ + half16;
    us16* bsw = Bs + ra * LDP_ + half16;

    unsigned av0[8], bv0[8], av1[8], bv1[8];
    GA_LOAD(0, av0, bv0);

    for (int ss = 0; ss < 11; ++ss) {
        __syncthreads();
        GA_STORE(av0, bv0);
        __syncthreads();
        GA_LOAD(2 * ss + 1, av1, bv1);
        GA_MFMA();
        __syncthreads();
        GA_STORE(av1, bv1);
        __syncthreads();
        if (ss < 10) GA_LOAD(2 * ss + 2, av0, bv0);
        GA_MFMA();
    }

#pragma unroll
    for (int i = 0; i < 4; ++i) {
#pragma unroll
        for (int j = 0; j < 4; ++j) {
            const int gm = m0 + wr * 64 + i * 16 + quad * 4;
            const int gn = n0 + wc * 64 + j * 16 + l16;
            us16* op = Apre + (long)gm * HK_ + gn;
#pragma unroll
            for (int r = 0; r < 4; ++r)
                op[(long)r * HK_] = f2bfu(acc[i][j][r]);
        }
    }
}

__global__ __launch_bounds__(64) void dhsfnn_wave(
    const us16* __restrict__ Apre,
    const void* __restrict__ b1,  const void* __restrict__ tau_n1,
    const void* __restrict__ tau_m1,
    const void* __restrict__ b2,  const void* __restrict__ tau_n2,
    const void* __restrict__ tau_m2,
    const void* __restrict__ Wr,  const void* __restrict__ br,
    const void* __restrict__ tau_mr,
    const us16* __restrict__ W2T,
    const int* __restrict__ warmup_p,
    void* __restrict__ out)
{
    const int lane = threadIdx.x;
    const int b    = blockIdx.x;
    const bool isb = detect_bf16((const us16*)tau_n1);
    const int wu   = *warmup_p;

    float be1[16], cb1[16], be2[16], cb2[16], d1[16], d2[16];
#pragma unroll
    for (int e = 0; e < 16; ++e) {
        const long gi = (long)lane * 16 + e;
        const float t1 = sigm(ldany(tau_n1, gi, isb));
        be1[e] = t1; cb1[e] = (1.f - t1) * ldany(b1, gi, isb);
        const float t2 = sigm(ldany(tau_n2, gi, isb));
        be2[e] = t2; cb2[e] = (1.f - t2) * ldany(b2, gi, isb);
        d1[e] = 0.f; d2[e] = 0.f;
    }
    float al1[4], al2[4], m1[4], s1[4], m2[4], s2[4];
#pragma unroll
    for (int j = 0; j < 4; ++j) {
        al1[j] = sigm(ldany(tau_m1, lane * 4 + j, isb));
        al2[j] = sigm(ldany(tau_m2, lane * 4 + j, isb));
        m1[j] = 0.f; s1[j] = 0.f; m2[j] = 0.f; s2[j] = 0.f;
    }
    float alr = 0.f, brv = 0.f;
    if (lane < O_) { alr = sigm(ldany(tau_mr, lane, isb)); brv = ldany(br, lane, isb); }
    float mrv = 0.f, accO = 0.f;

    const us16* ap = Apre + (long)b * T_ * HK_ + lane * 16;

    auto wstep = [&](int t, uint4 lo, uint4 hi) {
        float a[16];
        a[0]=bflo(lo.x);  a[1]=bfhi(lo.x);  a[2]=bflo(lo.y);  a[3]=bfhi(lo.y);
        a[4]=bflo(lo.z);  a[5]=bfhi(lo.z);  a[6]=bflo(lo.w);  a[7]=bfhi(lo.w);
        a[8]=bflo(hi.x);  a[9]=bfhi(hi.x);  a[10]=bflo(hi.y); a[11]=bfhi(hi.y);
        a[12]=bflo(hi.z); a[13]=bfhi(hi.z); a[14]=bflo(hi.w); a[15]=bfhi(hi.w);
#pragma unroll
        for (int e = 0; e < 16; ++e)
            d1[e] = be1[e] * d1[e] + cb1[e] + (1.f - be1[e]) * a[e];
        unsigned long long bal1[4];
#pragma unroll
        for (int j = 0; j < 4; ++j) {
            const float s = (d1[j*4+0] + d1[j*4+1]) + (d1[j*4+2] + d1[j*4+3]);
            m1[j] = m1[j] * al1[j] + (1.f - al1[j]) * s - s1[j];
            s1[j] = (m1[j] > 1.0f) ? 1.f : 0.f;
            bal1[j] = __ballot(s1[j] > 0.f);
        }
        if ((bal1[0] | bal1[1] | bal1[2] | bal1[3]) != 0ull) {
            float g[16];
#pragma unroll
            for (int e = 0; e < 16; ++e) g[e] = 0.f;
            for (int j2 = 0; j2 < 4; ++j2) {
                unsigned long long mm = bal1[j2];
                while (mm) {
                    const int i = __ffsll(mm) - 1; mm &= mm - 1;
                    const us16* wv = W2T + ((long)(i * 4 + j2) << 10) + lane * 16;
                    const uint4 wl = *(const uint4*)wv;
                    const uint4 wh = *(const uint4*)(wv + 8);
                    g[0]+=bflo(wl.x);  g[1]+=bfhi(wl.x);  g[2]+=bflo(wl.y);  g[3]+=bfhi(wl.y);
                    g[4]+=bflo(wl.z);  g[5]+=bfhi(wl.z);  g[6]+=bflo(wl.w);  g[7]+=bfhi(wl.w);
                    g[8]+=bflo(wh.x);  g[9]+=bfhi(wh.x);  g[10]+=bflo(wh.y); g[11]+=bfhi(wh.y);
                    g[12]+=bflo(wh.z); g[13]+=bfhi(wh.z); g[14]+=bflo(wh.w); g[15]+=bfhi(wh.w);
                }
            }
#pragma unroll
            for (int e = 0; e < 16; ++e)
                d2[e] = be2[e] * d2[e] + cb2[e] + (1.f - be2[e]) * g[e];
        } else {
#pragma unroll
            for (int e = 0; e < 16; ++e)
                d2[e] = be2[e] * d2[e] + cb2[e];
        }
        unsigned long long bal2[4];
#pragma unroll
        for (int j = 0; j < 4; ++j) {
            const float s = (d2[j*4+0] + d2[j*4+1]) + (d2[j*4+2] + d2[j*4+3]);
            m2[j] = m2[j] * al2[j] + (1.f - al2[j]) * s - s2[j];
            s2[j] = (m2[j] > 1.0f) ? 1.f : 0.f;
            bal2[j] = __ballot(s2[j] > 0.f);
        }
        if (lane < O_) {
            float sum = brv;
            if ((bal2[0] | bal2[1] | bal2[2] | bal2[3]) != 0ull) {
                for (int j2 = 0; j2 < 4; ++j2) {
                    unsigned long long mm = bal2[j2];
                    while (mm) {
                        const int i = __ffsll(mm) - 1; mm &= mm - 1;
                        sum += ldany(Wr, (long)lane * H_ + (i * 4 + j2), isb);
                    }
                }
            }
            mrv = alr * mrv + (1.f - alr) * sum;
            if (t >= wu) accO += mrv;
        }
    };

    uint4 q0a = *(const uint4*)(ap);
    uint4 q0b = *(const uint4*)(ap + 8);
    uint4 q1a = *(const uint4*)(ap + HK_);
    uint4 q1b = *(const uint4*)(ap + HK_ + 8);
    uint4 q2a = *(const uint4*)(ap + 2 * HK_);
    uint4 q2b = *(const uint4*)(ap + 2 * HK_ + 8);
    uint4 q3a = *(const uint4*)(ap + 3 * HK_);
    uint4 q3b = *(const uint4*)(ap + 3 * HK_ + 8);

    int t = 0;
    for (int it = 0; it < 62; ++it) {
        wstep(t + 0, q0a, q0b);
        q0a = *(const uint4*)(ap + (long)(t + 4) * HK_);
        q0b = *(const uint4*)(ap + (long)(t + 4) * HK_ + 8);
        wstep(t + 1, q1a, q1b);
        if (t + 5 < T_) {
            q1a = *(const uint4*)(ap + (long)(t + 5) * HK_);
            q1b = *(const uint4*)(ap + (long)(t + 5) * HK_ + 8);
        }
        wstep(t + 2, q2a, q2b);
        if (t + 6 < T_) {
            q2a = *(const uint4*)(ap + (long)(t + 6) * HK_);
            q2b = *(const uint4*)(ap + (long)(t + 6) * HK_ + 8);
        }
        wstep(t + 3, q3a, q3b);
        if (t + 7 < T_) {
            q3a = *(const uint4*)(ap + (long)(t + 7) * HK_);
            q3b = *(const uint4*)(ap + (long)(t + 7) * HK_ + 8);
        }
        t += 4;
    }
    wstep(248, q0a, q0b);
    wstep(249, q1a, q1b);

    if (lane < O_) {
        const float res = accO / (float)(T_ - wu);
        if (isb) ((us16*)out)[b * O_ + lane] = f2bfu(res);
        else     ((float*)out)[b * O_ + lane] = res;
    }
}

// ---------------------------------------------------------------------------
// Tier-3 fallback: no workspace at all (round-2 proven).
// ---------------------------------------------------------------------------
__global__ __launch_bounds__(256) void dhsfnn_fb(
    const void* __restrict__ x,  const void* __restrict__ W1,
    const void* __restrict__ b1, const void* __restrict__ tau_n1,
    const void* __restrict__ tau_m1,
    const void* __restrict__ W2, const void* __restrict__ b2,
    const void* __restrict__ tau_n2, const void* __restrict__ tau_m2,
    const void* __restrict__ Wr, const void* __restrict__ br,
    const void* __restrict__ tau_mr,
    const int* __restrict__ warmup_p,
    void* __restrict__ out)
{
    __shared__ us16 list1[1024];
    __shared__ us16 list2[256];
    __shared__ us16 list3[256];
    __shared__ int n1s, n2s, n3s;

    const int tid = threadIdx.x;
    const int b   = blockIdx.x;
    const int h   = tid;
    const bool isb = detect_bf16((const us16*)tau_n1);
    const int wu  = *warmup_p;

    const float be1_0 = sigm(ldany(tau_n1, 4 * h + 0, isb));
    const float be1_1 = sigm(ldany(tau_n1, 4 * h + 1, isb));
    const float be1_2 = sigm(ldany(tau_n1, 4 * h + 2, isb));
    const float be1_3 = sigm(ldany(tau_n1, 4 * h + 3, isb));
    const float bi1_0 = ldany(b1, 4 * h + 0, isb), bi1_1 = ldany(b1, 4 * h + 1, isb);
    const float bi1_2 = ldany(b1, 4 * h + 2, isb), bi1_3 = ldany(b1, 4 * h + 3, isb);
    const float al1 = sigm(ldany(tau_m1, h, isb));
    const float be2_0 = sigm(ldany(tau_n2, 4 * h + 0, isb));
    const float be2_1 = sigm(ldany(tau_n2, 4 * h + 1, isb));
    const float be2_2 = sigm(ldany(tau_n2, 4 * h + 2, isb));
    const float be2_3 = sigm(ldany(tau_n2, 4 * h + 3, isb));
    const float bi2_0 = ldany(b2, 4 * h + 0, isb), bi2_1 = ldany(b2, 4 * h + 1, isb);
    const float bi2_2 = ldany(b2, 4 * h + 2, isb), bi2_3 = ldany(b2, 4 * h + 3, isb);
    const float al2 = sigm(ldany(tau_m2, h, isb));
    float alr = 0.f, brv = 0.f;
    if (h < O_) { alr = sigm(ldany(tau_mr, h, isb)); brv = ldany(br, h, isb); }

    float d1_0 = 0.f, d1_1 = 0.f, d1_2 = 0.f, d1_3 = 0.f, m1v = 0.f, s1f = 0.f;
    float d2_0 = 0.f, d2_1 = 0.f, d2_2 = 0.f, d2_3 = 0.f, m2v = 0.f, s2f = 0.f;
    float mrv = 0.f, accO = 0.f;

    const long xbase = (long)b * T_ * IN_;
    float xv0 = ldany(x, xbase + tid, isb);
    float xv1 = ldany(x, xbase + tid + 256, isb);
    float xv2 = (tid + 512 < IN_) ? ldany(x, xbase + tid + 512, isb) : 0.f;

    for (int t = 0; t < T_; ++t) {
        const bool p0 = xv0 != 0.f, p1 = xv1 != 0.f, p2 = xv2 != 0.f;
        if (t + 1 < T_) {
            const long nbx = xbase + (long)(t + 1) * IN_;
            xv0 = ldany(x, nbx + tid, isb);
            xv1 = ldany(x, nbx + tid + 256, isb);
            xv2 = (tid + 512 < IN_) ? ldany(x, nbx + tid + 512, isb) : 0.f;
        }
        __syncthreads();
        if (tid == 0) { n1s = 0; n2s = 0; n3s = 0; }
        __syncthreads();
        if (p0) { int p = atomicAdd(&n1s, 1); list1[p & 1023] = (us16)tid; }
        if (p1) { int p = atomicAdd(&n1s, 1); list1[p & 1023] = (us16)(tid + 256); }
        if (p2) { int p = atomicAdd(&n1s, 1); list1[p & 1023] = (us16)(tid + 512); }
        __syncthreads();
        int n1 = n1s; n1 = (n1 < 1024) ? n1 : 1024;

        float a0 = 0.f, a1 = 0.f, a2 = 0.f, a3 = 0.f;
#pragma unroll 2
        for (int idx = 0; idx < n1; ++idx) {
            int i = rfl((int)list1[idx]);
            i = (i < IN_) ? i : (IN_ - 1);
            long r = (long)(h * 4) * IN_ + i;
            a0 += ldany(W1, r, isb);
            a1 += ldany(W1, r + IN_, isb);
            a2 += ldany(W1, r + 2 * IN_, isb);
            a3 += ldany(W1, r + 3 * IN_, isb);
        }
        d1_0 = be1_0 * d1_0 + (1.f - be1_0) * (bi1_0 + a0);
        d1_1 = be1_1 * d1_1 + (1.f - be1_1) * (bi1_1 + a1);
        d1_2 = be1_2 * d1_2 + (1.f - be1_2) * (bi1_2 + a2);
        d1_3 = be1_3 * d1_3 + (1.f - be1_3) * (bi1_3 + a3);
        m1v = m1v * al1 + (1.f - al1) * (d1_0 + d1_1 + d1_2 + d1_3) - s1f;
        s1f = (m1v > 1.0f) ? 1.f : 0.f;

        if (s1f > 0.f) { int p = atomicAdd(&n2s, 1); list2[p & 255] = (us16)tid; }
        __syncthreads();
        int n2 = n2s; n2 = (n2 < 256) ? n2 : 256;

        a0 = 0.f; a1 = 0.f; a2 = 0.f; a3 = 0.f;
#pragma unroll 2
        for (int idx = 0; idx < n2; ++idx) {
            int i = rfl((int)list2[idx]);
            i = (i < H_) ? i : (H_ - 1);
            long r = (long)(h * 4) * H_ + i;
            a0 += ldany(W2, r, isb);
            a1 += ldany(W2, r + H_, isb);
            a2 += ldany(W2, r + 2 * H_, isb);
            a3 += ldany(W2, r + 3 * H_, isb);
        }
        d2_0 = be2_0 * d2_0 + (1.f - be2_0) * (bi2_0 + a0);
        d2_1 = be2_1 * d2_1 + (1.f - be2_1) * (bi2_1 + a1);
        d2_2 = be2_2 * d2_2 + (1.f - be2_2) * (bi2_2 + a2);
        d2_3 = be2_3 * d2_3 + (1.f - be2_3) * (bi2_3 + a3);
        m2v = m2v * al2 + (1.f - al2) * (d2_0 + d2_1 + d2_2 + d2_3) - s2f;
        s2f = (m2v > 1.0f) ? 1.f : 0.f;

        if (s2f > 0.f) { int p = atomicAdd(&n3s, 1); list3[p & 255] = (us16)tid; }
        __syncthreads();
        int n3 = n3s; n3 = (n3 < 256) ? n3 : 256;

        if (h < O_) {
            float sum = brv;
            for (int idx = 0; idx < n3; ++idx) {
                int j = (int)list3[idx];
                j = (j < H_) ? j : (H_ - 1);
                sum += ldany(Wr, (long)h * H_ + j, isb);
            }
            mrv = alr * mrv + (1.f - alr) * sum;
            if (t >= wu) accO += mrv;
        }
    }
    if (h < O_) {
        float res = accO / (float)(T_ - wu);
        if (isb) ((us16*)out)[b * O_ + h] = f2bfu(res);
        else     ((float*)out)[b * O_ + h] = res;
    }
}

// ---------------------------------------------------------------------------
extern "C" void kernel_launch(void* const* d_in, const int* in_sizes, int n_in,
                              void* d_out, int out_size, void* d_ws, size_t ws_size,
                              hipStream_t stream) {
    const void* x      = d_in[0];
    const void* W1     = d_in[1];
    const void* b1     = d_in[2];
    const void* tau_n1 = d_in[3];
    const void* tau_m1 = d_in[4];
    const void* W2     = d_in[5];
    const void* b2     = d_in[6];
    const void* tau_n2 = d_in[7];
    const void* tau_m2 = d_in[8];
    const void* Wr     = d_in[9];
    const void* br     = d_in[10];
    const void* tau_mr = d_in[11];
    const int*  warmup = (const int*)d_in[12];

    const size_t w2t_bytes  = (size_t)H_ * HK_ * 2;            //     524,288
    const size_t xbf_bytes  = (size_t)NPAIR_ * KP_ * 2;        //  90,112,000
    const size_t w1b_bytes  = (size_t)HK_ * KP_ * 2;           //   1,441,792
    const size_t apre_bytes = (size_t)NPAIR_ * HK_ * 2;        // 131,072,000

    const bool tier0 = (d_ws != nullptr &&
                        ws_size >= w2t_bytes + xbf_bytes + w1b_bytes + apre_bytes);
    const bool tier1 = (d_ws != nullptr && ws_size >= w2t_bytes + apre_bytes);

    dim3 blk(32, 8);
    if (tier0) {
        us16* W2T  = (us16*)d_ws;
        us16* Xbf  = (us16*)((char*)d_ws + w2t_bytes);
        us16* W1bf = (us16*)((char*)d_ws + w2t_bytes + xbf_bytes);
        us16* Apre = (us16*)((char*)d_ws + w2t_bytes + xbf_bytes + w1b_bytes);
        cvt_rows2<<<(NPAIR_ + HK_) / 4, 256, 0, stream>>>(
            x, W1, Xbf, W1bf, (const us16*)tau_n1);
        transpose_to_bf16<<<dim3((H_ + 31) / 32, (HK_ + 31) / 32), blk, 0, stream>>>(
            W2, W2T, HK_, H_, (const us16*)tau_n1);
        gemm_bf<<<4096, 256, 0, stream>>>(Xbf, W1bf, Apre);
        dhsfnn_pc<<<B_, 256, 0, stream>>>(
            Apre, b1, tau_n1, tau_m1, b2, tau_n2, tau_m2,
            Wr, br, tau_mr, W2T, warmup, d_out);
    } else if (tier1) {
        us16* W2T  = (us16*)d_ws;
        us16* Apre = (us16*)((char*)d_ws + w2t_bytes);
        transpose_to_bf16<<<dim3((H_ + 31) / 32, (HK_ + 31) / 32), blk, 0, stream>>>(
            W2, W2T, HK_, H_, (const us16*)tau_n1);
        gemm_apre<<<4096, 256, 0, stream>>>(x, W1, (const us16*)tau_n1, Apre);
        dhsfnn_wave<<<B_, 64, 0, stream>>>(
            Apre, b1, tau_n1, tau_m1, b2, tau_n2, tau_m2,
            Wr, br, tau_mr, W2T, warmup, d_out);
    } else {
        dhsfnn_fb<<<B_, 256, 0, stream>>>(x, W1, b1, tau_n1, tau_m1,
                                          W2, b2, tau_n2, tau_m2,
                                          Wr, br, tau_mr, warmup, d_out);
    }
}

// Round 15
// 458.031 us; speedup vs baseline: 1.2069x; 1.0091x over previous
//
#include <hip/hip_runtime.h>
#include <hip/hip_bf16.h>

typedef unsigned short us16;
typedef unsigned int u32;

#define B_   256
#define T_   250
#define IN_  700
#define KP_  704           // K padded
#define H_   256
#define O_   20
#define HK_  1024
#define NPAIR_ (B_ * T_)   // 64000
#define LDP_ 40            // tier-1 LDS pitch
#define CP_  132           // epilogue C-tile pitch (elems)

typedef __attribute__((ext_vector_type(8))) short short8;
typedef __attribute__((ext_vector_type(4))) float f32x4;

__device__ __forceinline__ float bfbits(unsigned int lo16) {
    union { unsigned int i; float f; } v; v.i = lo16 << 16; return v.f;
}
__device__ __forceinline__ float bflo(unsigned int u) {
    union { unsigned int i; float f; } v; v.i = u << 16; return v.f;
}
__device__ __forceinline__ float bfhi(unsigned int u) {
    union { unsigned int i; float f; } v; v.i = u & 0xffff0000u; return v.f;
}
__device__ __forceinline__ us16 f2bfu(float f) {
    __hip_bfloat16 h = __float2bfloat16(f);
    union { __hip_bfloat16 h; us16 u; } c; c.h = h; return c.u;
}
__device__ __forceinline__ float sigm(float x) { return 1.0f / (1.0f + expf(-x)); }
__device__ __forceinline__ int rfl(int v) { return __builtin_amdgcn_readfirstlane(v); }

// tau_n1 uniform in [2,6): bf16 => every value ushort has high byte 0x40.
// (Round-5 counters proved this dataset is fp32.)
__device__ __forceinline__ bool detect_bf16(const us16* __restrict__ taun) {
    int ok = 0;
#pragma unroll
    for (int i = 0; i < 8; i += 2) ok += ((taun[i] >> 8) == 0x40) ? 1 : 0;
    return ok == 4;
}
__device__ __forceinline__ float ldany(const void* __restrict__ p, long i, bool isb) {
    return isb ? bfbits(((const us16*)p)[i]) : ((const float*)p)[i];
}

// async global->LDS, 16B per lane; lds base must be wave-uniform.
__device__ __forceinline__ void async_cp16(const us16* g, us16* l) {
    __builtin_amdgcn_global_load_lds(
        (const __attribute__((address_space(1))) u32*)g,
        (__attribute__((address_space(3))) u32*)l, 16, 0, 0);
}

// ---------------------------------------------------------------------------
// Merged row convert+pad for X and W1 (one launch): [*,700] -> [*,704] bf16.
// One wave per row; float4 loads + uint2 stores (700 = 175x4; chunk 175 = pad).
// ---------------------------------------------------------------------------
__global__ __launch_bounds__(256) void cvt_rows2(
    const void* __restrict__ xin, const void* __restrict__ w1in,
    us16* __restrict__ xout, us16* __restrict__ w1out,
    const us16* __restrict__ taun) {
    const bool isb = detect_bf16(taun);
    const int r = blockIdx.x * 4 + (threadIdx.x >> 6);
    const int l = threadIdx.x & 63;
    const void* in; us16* out; long ibase, obase;
    if (r < NPAIR_) {
        in = xin;  out = xout;  ibase = (long)r * IN_; obase = (long)r * KP_;
    } else {
        const int r2 = r - NPAIR_;
        if (r2 >= HK_) return;
        in = w1in; out = w1out; ibase = (long)r2 * IN_; obase = (long)r2 * KP_;
    }
    for (int c = l; c < 176; c += 64) {
        uint2 o;
        if (c < 175) {
            if (isb) {
                o = *(const uint2*)((const us16*)in + ibase + 4 * c);
            } else {
                float4 f = *(const float4*)((const float*)in + ibase + 4 * c);
                o.x = (u32)f2bfu(f.x) | ((u32)f2bfu(f.y) << 16);
                o.y = (u32)f2bfu(f.z) | ((u32)f2bfu(f.w) << 16);
            }
        } else { o.x = 0u; o.y = 0u; }
        *(uint2*)(out + obase + 4 * c) = o;
    }
}

// ---------------------------------------------------------------------------
__global__ void transpose_to_bf16(const void* __restrict__ in, us16* __restrict__ out,
                                  int R, int C, const us16* __restrict__ taun) {
    const bool isb = detect_bf16(taun);
    __shared__ us16 tile[32][33];
    int c0 = blockIdx.x * 32, r0 = blockIdx.y * 32;
    int tx = threadIdx.x, ty = threadIdx.y;   // block (32,8)
#pragma unroll
    for (int j = 0; j < 32; j += 8) {
        int r = r0 + ty + j, c = c0 + tx;
        if (r < R && c < C) tile[ty + j][tx] = f2bfu(ldany(in, (long)r * C + c, isb));
    }
    __syncthreads();
#pragma unroll
    for (int j = 0; j < 32; j += 8) {
        int c = c0 + ty + j, r = r0 + tx;
        if (c < C && r < R) out[(long)c * R + r] = tile[tx][ty + j];
    }
}

// ---------------------------------------------------------------------------
// Tier-0 GEMM (round-14 proven), DOUBLE-BUFFERED LDS, one barrier/step:
// Apre[64000,1024] = Xb[64000,704] · W1b[1024,704]^T, bf16, BM=128, BK=64.
// ---------------------------------------------------------------------------
__global__ __launch_bounds__(256) void gemm_bf(
    const us16* __restrict__ Xb, const us16* __restrict__ W1b,
    us16* __restrict__ Apre)
{
    // buf0: A [0,8192) B [8192,16384); buf1: A [16384,24576) B [24576,32768)
    __shared__ __align__(16) us16 smem[32768];   // 64 KB

    const int L  = blockIdx.x;
    const int mt = (L & 7) + ((L >> 6) << 3);
    const int nt = (L >> 3) & 7;
    if (mt >= NPAIR_ / 128) return;
    const int m0 = mt * 128, n0 = nt * 128;

    const int tid  = threadIdx.x;
    const int lane = tid & 63;
    const int w    = tid >> 6;
    const int wr   = w >> 1, wc = w & 1;
    const int l16  = lane & 15, quad = lane >> 4;

    const int rr    = lane >> 3;
    const int ccsw  = ((lane & 7) ^ rr) * 8;         // swizzled chunk start (elems)
    const us16* xg[4]; const us16* wg[4];
    int asl[4], bsl[4];
#pragma unroll
    for (int i = 0; i < 4; ++i) {
        const int blkrow = (w * 4 + i) * 8;
        xg[i]  = Xb  + (long)(m0 + blkrow + rr) * KP_ + ccsw;
        wg[i]  = W1b + (long)(n0 + blkrow + rr) * KP_ + ccsw;
        asl[i] = (w * 4 + i) * 512;
        bsl[i] = 8192 + (w * 4 + i) * 512;
    }

    f32x4 acc[4][4];
#pragma unroll
    for (int i = 0; i < 4; ++i)
#pragma unroll
        for (int j = 0; j < 4; ++j) acc[i][j] = (f32x4){0.f, 0.f, 0.f, 0.f};

    const int sw = l16 & 7;
    int aoff0[4], aoff1[4], boff0[4], boff1[4];
#pragma unroll
    for (int i = 0; i < 4; ++i) {
        const int ar = wr * 64 + i * 16 + l16;
        const int br = wc * 64 + i * 16 + l16;
        aoff0[i] = ar * 64 + ((quad ^ sw) << 3);
        aoff1[i] = ar * 64 + (((quad + 4) ^ sw) << 3);
        boff0[i] = 8192 + br * 64 + ((quad ^ sw) << 3);
        boff1[i] = 8192 + br * 64 + (((quad + 4) ^ sw) << 3);
    }

    // prologue: stage step 0 into buf0
#pragma unroll
    for (int i = 0; i < 4; ++i) async_cp16(xg[i], smem + asl[i]);
#pragma unroll
    for (int i = 0; i < 4; ++i) async_cp16(wg[i], smem + bsl[i]);
    __syncthreads();

    for (int s = 0; s < 11; ++s) {             // 11 * 64 = 704
        const int cur = (s & 1) * 16384;
        const int nxt = 16384 - cur;
        if (s + 1 < 11) {                      // issue s+1 loads into idle buffer
            const int kb = (s + 1) * 64;
#pragma unroll
            for (int i = 0; i < 4; ++i) async_cp16(xg[i] + kb, smem + nxt + asl[i]);
#pragma unroll
            for (int i = 0; i < 4; ++i) async_cp16(wg[i] + kb, smem + nxt + bsl[i]);
        }

        short8 af[4][2], bfv[4][2];
#pragma unroll
        for (int i = 0; i < 4; ++i) {
            af[i][0]  = *(const short8*)(smem + cur + aoff0[i]);
            af[i][1]  = *(const short8*)(smem + cur + aoff1[i]);
            bfv[i][0] = *(const short8*)(smem + cur + boff0[i]);
            bfv[i][1] = *(const short8*)(smem + cur + boff1[i]);
        }
#pragma unroll
        for (int h = 0; h < 2; ++h)
#pragma unroll
            for (int i = 0; i < 4; ++i)
#pragma unroll
                for (int j = 0; j < 4; ++j)
                    acc[i][j] = __builtin_amdgcn_mfma_f32_16x16x32_bf16(
                        af[i][h], bfv[j][h], acc[i][j], 0, 0, 0);

        __syncthreads();   // drains s+1 asyncs (flew under MFMAs); frees cur
    }

    // epilogue: stage C-tile in LDS (reuse smem), coalesced 256 B rows
#pragma unroll
    for (int i = 0; i < 4; ++i)
#pragma unroll
        for (int j = 0; j < 4; ++j)
#pragma unroll
            for (int r = 0; r < 4; ++r)
                smem[(wr * 64 + i * 16 + quad * 4 + r) * CP_ +
                     (wc * 64 + j * 16 + l16)] = f2bfu(acc[i][j][r]);
    __syncthreads();
    for (int r2 = 0; r2 < 32; ++r2) {
        const int row = w * 32 + r2;
        const u32 v = *(const u32*)(smem + row * CP_ + lane * 2);
        *(u32*)(Apre + (long)(m0 + row) * HK_ + n0 + lane * 2) = v;
    }
}

// ---------------------------------------------------------------------------
// Tier-0 phase 2 v3: producer-consumer with ASYNC producers. Producer copies
// go global_load_lds (fire-and-forget, no register round trip) — round-14
// counters showed dst[k]=src[k] producers capped at 639 GB/s (1-2 loads in
// flight per lane); async issues ~11 1KB instrs back-to-back per wave, and
// the chunk-boundary __syncthreads drains vmcnt with identical semantics.
// ---------------------------------------------------------------------------
__global__ __launch_bounds__(256) void dhsfnn_pc(
    const us16* __restrict__ Apre,
    const void* __restrict__ b1,  const void* __restrict__ tau_n1,
    const void* __restrict__ tau_m1,
    const void* __restrict__ b2,  const void* __restrict__ tau_n2,
    const void* __restrict__ tau_m2,
    const void* __restrict__ Wr,  const void* __restrict__ br,
    const void* __restrict__ tau_mr,
    const us16* __restrict__ W2T,      // [presyn 256][elem 1024] bf16
    const int* __restrict__ warmup_p,
    void* __restrict__ out)
{
    __shared__ __align__(16) us16 ring[2][16 * HK_];   // 2 x 32 KB

    const int tid  = threadIdx.x;
    const int lane = tid & 63;
    const int w    = tid >> 6;
    const int b    = blockIdx.x;
    const bool isb = detect_bf16((const us16*)tau_n1);
    const int wu   = *warmup_p;

    const us16* apb = Apre + (long)b * T_ * HK_;

    // chunk 0: all 4 waves issue async copies (32 segments x 512 elems = 32 KB);
    // they fly under the constants-loading phase below, drained at the barrier.
    for (int seg = w; seg < 32; seg += 4)
        async_cp16(apb + seg * 512 + lane * 8, ring[0] + seg * 512);

    float be1[16], cb1[16], ce1[16], be2[16], cb2[16], ce2[16], d1[16], d2[16];
#pragma unroll
    for (int e = 0; e < 16; ++e) {
        const long gi = (e < 8) ? ((long)lane * 8 + e) : (512 + (long)lane * 8 + e - 8);
        const float t1 = sigm(ldany(tau_n1, gi, isb));
        be1[e] = t1; ce1[e] = 1.f - t1; cb1[e] = ce1[e] * ldany(b1, gi, isb);
        const float t2 = sigm(ldany(tau_n2, gi, isb));
        be2[e] = t2; ce2[e] = 1.f - t2; cb2[e] = ce2[e] * ldany(b2, gi, isb);
        d1[e] = 0.f; d2[e] = 0.f;
    }
    float al1[4], al2[4], m1[4], s1[4], m2[4], s2[4];
#pragma unroll
    for (int j = 0; j < 4; ++j) {
        const int n = (j < 2) ? (2 * lane + j) : (128 + 2 * lane + (j - 2));
        al1[j] = sigm(ldany(tau_m1, n, isb));
        al2[j] = sigm(ldany(tau_m2, n, isb));
        m1[j] = 0.f; s1[j] = 0.f; m2[j] = 0.f; s2[j] = 0.f;
    }
    float alr = 0.f, brv = 0.f;
    if (lane < O_) { alr = sigm(ldany(tau_mr, lane, isb)); brv = ldany(br, lane, isb); }
    float mrv = 0.f, accO = 0.f;

    __syncthreads();                     // drains chunk-0 asyncs

    for (int c = 0; c < 16; ++c) {
        const int t0 = c * 16;
        const int nst = (T_ - t0 < 16) ? (T_ - t0) : 16;

        if (w != 0) {
            if (c + 1 < 16) {            // producers: async-load chunk c+1
                const int t1c  = (c + 1) * 16;
                const int nseg = ((T_ - t1c < 16) ? (T_ - t1c) : 16) * 2;
                const us16* src = apb + (long)t1c * HK_;
                us16* dst = ring[(c + 1) & 1];
                for (int seg = w - 1; seg < nseg; seg += 3)
                    async_cp16(src + seg * 512 + lane * 8, dst + seg * 512);
            }
        } else {
            const us16* rb = ring[c & 1];
            uint4 cLo = *(const uint4*)(rb + lane * 8);
            uint4 cHi = *(const uint4*)(rb + 512 + lane * 8);
            for (int q = 0; q < nst; ++q) {
                uint4 nLo = cLo, nHi = cHi;
                if (q + 1 < nst) {       // prefetch next step's row
                    nLo = *(const uint4*)(rb + (q + 1) * HK_ + lane * 8);
                    nHi = *(const uint4*)(rb + (q + 1) * HK_ + 512 + lane * 8);
                }
                const int t = t0 + q;
                float a[16];
                a[0]=bflo(cLo.x);  a[1]=bfhi(cLo.x);  a[2]=bflo(cLo.y);  a[3]=bfhi(cLo.y);
                a[4]=bflo(cLo.z);  a[5]=bfhi(cLo.z);  a[6]=bflo(cLo.w);  a[7]=bfhi(cLo.w);
                a[8]=bflo(cHi.x);  a[9]=bfhi(cHi.x);  a[10]=bflo(cHi.y); a[11]=bfhi(cHi.y);
                a[12]=bflo(cHi.z); a[13]=bfhi(cHi.z); a[14]=bflo(cHi.w); a[15]=bfhi(cHi.w);

#pragma unroll
                for (int e = 0; e < 16; ++e)
                    d1[e] = be1[e] * d1[e] + cb1[e] + ce1[e] * a[e];

                unsigned long long bal1[4];
#pragma unroll
                for (int j = 0; j < 4; ++j) {
                    const float s = (d1[j*4+0] + d1[j*4+1]) + (d1[j*4+2] + d1[j*4+3]);
                    m1[j] = m1[j] * al1[j] + (1.f - al1[j]) * s - s1[j];
                    s1[j] = (m1[j] > 1.0f) ? 1.f : 0.f;
                    bal1[j] = __ballot(s1[j] > 0.f);
                }

                if ((bal1[0] | bal1[1] | bal1[2] | bal1[3]) != 0ull) {   // rare
                    float g[16];
#pragma unroll
                    for (int e = 0; e < 16; ++e) g[e] = 0.f;
                    for (int j2 = 0; j2 < 4; ++j2) {
                        unsigned long long mm = bal1[j2];
                        while (mm) {
                            const int i = __ffsll(mm) - 1; mm &= mm - 1;
                            const int n = (j2 < 2) ? (2 * i + j2) : (128 + 2 * i + (j2 - 2));
                            const us16* wv = W2T + ((long)n << 10);
                            const uint4 wl = *(const uint4*)(wv + lane * 8);
                            const uint4 wh = *(const uint4*)(wv + 512 + lane * 8);
                            g[0]+=bflo(wl.x);  g[1]+=bfhi(wl.x);  g[2]+=bflo(wl.y);  g[3]+=bfhi(wl.y);
                            g[4]+=bflo(wl.z);  g[5]+=bfhi(wl.z);  g[6]+=bflo(wl.w);  g[7]+=bfhi(wl.w);
                            g[8]+=bflo(wh.x);  g[9]+=bfhi(wh.x);  g[10]+=bflo(wh.y); g[11]+=bfhi(wh.y);
                            g[12]+=bflo(wh.z); g[13]+=bfhi(wh.z); g[14]+=bflo(wh.w); g[15]+=bfhi(wh.w);
                        }
                    }
#pragma unroll
                    for (int e = 0; e < 16; ++e)
                        d2[e] = be2[e] * d2[e] + cb2[e] + ce2[e] * g[e];
                } else {
#pragma unroll
                    for (int e = 0; e < 16; ++e)
                        d2[e] = be2[e] * d2[e] + cb2[e];
                }

                unsigned long long bal2[4];
#pragma unroll
                for (int j = 0; j < 4; ++j) {
                    const float s = (d2[j*4+0] + d2[j*4+1]) + (d2[j*4+2] + d2[j*4+3]);
                    m2[j] = m2[j] * al2[j] + (1.f - al2[j]) * s - s2[j];
                    s2[j] = (m2[j] > 1.0f) ? 1.f : 0.f;
                    bal2[j] = __ballot(s2[j] > 0.f);
                }

                if (lane < O_) {
                    float sum = brv;
                    if ((bal2[0] | bal2[1] | bal2[2] | bal2[3]) != 0ull) {
                        for (int j2 = 0; j2 < 4; ++j2) {
                            unsigned long long mm = bal2[j2];
                            while (mm) {
                                const int i = __ffsll(mm) - 1; mm &= mm - 1;
                                const int n = (j2 < 2) ? (2 * i + j2) : (128 + 2 * i + (j2 - 2));
                                sum += ldany(Wr, (long)lane * H_ + n, isb);
                            }
                        }
                    }
                    mrv = alr * mrv + (1.f - alr) * sum;
                    if (t >= wu) accO += mrv;
                }
                cLo = nLo; cHi = nHi;
            }
        }
        __syncthreads();                 // chunk boundary: drains producer asyncs
    }

    if (w == 0 && lane < O_) {
        const float res = accO / (float)(T_ - wu);
        if (isb) ((us16*)out)[b * O_ + lane] = f2bfu(res);
        else     ((float*)out)[b * O_ + lane] = res;
    }
}

// ===========================================================================
// Tier-1 fallback: round-8 proven pair (fp32-direct GEMM + 1-wave recurrence)
// ===========================================================================
#define GA_LOAD(S, AV, BV) do {                                               \
    const int k0_ = (S) * 32 + half16;                                        \
    if (k0_ + 16 <= IN_) {                                                    \
        if (isb) {                                                            \
            const us16* pa_ = (const us16*)X  + arow + k0_;                   \
            const us16* pb_ = (const us16*)W1 + brow + k0_;                   \
            uint2 a0_ = *(const uint2*)pa_,        a1_ = *(const uint2*)(pa_ + 4);  \
            uint2 a2_ = *(const uint2*)(pa_ + 8),  a3_ = *(const uint2*)(pa_ + 12); \
            uint2 b0_ = *(const uint2*)pb_,        b1_ = *(const uint2*)(pb_ + 4);  \
            uint2 b2_ = *(const uint2*)(pb_ + 8),  b3_ = *(const uint2*)(pb_ + 12); \
            AV[0]=a0_.x; AV[1]=a0_.y; AV[2]=a1_.x; AV[3]=a1_.y;               \
            AV[4]=a2_.x; AV[5]=a2_.y; AV[6]=a3_.x; AV[7]=a3_.y;               \
            BV[0]=b0_.x; BV[1]=b0_.y; BV[2]=b1_.x; BV[3]=b1_.y;               \
            BV[4]=b2_.x; BV[5]=b2_.y; BV[6]=b3_.x; BV[7]=b3_.y;               \
        } else {                                                              \
            const float* pa_ = (const float*)X  + arow + k0_;                 \
            const float* pb_ = (const float*)W1 + brow + k0_;                 \
            float4 fa0_ = *(const float4*)pa_,        fa1_ = *(const float4*)(pa_ + 4);  \
            float4 fa2_ = *(const float4*)(pa_ + 8),  fa3_ = *(const float4*)(pa_ + 12); \
            float4 fb0_ = *(const float4*)pb_,        fb1_ = *(const float4*)(pb_ + 4);  \
            float4 fb2_ = *(const float4*)(pb_ + 8),  fb3_ = *(const float4*)(pb_ + 12); \
            AV[0] = (unsigned)f2bfu(fa0_.x) | ((unsigned)f2bfu(fa0_.y) << 16); \
            AV[1] = (unsigned)f2bfu(fa0_.z) | ((unsigned)f2bfu(fa0_.w) << 16); \
            AV[2] = (unsigned)f2bfu(fa1_.x) | ((unsigned)f2bfu(fa1_.y) << 16); \
            AV[3] = (unsigned)f2bfu(fa1_.z) | ((unsigned)f2bfu(fa1_.w) << 16); \
            AV[4] = (unsigned)f2bfu(fa2_.x) | ((unsigned)f2bfu(fa2_.y) << 16); \
            AV[5] = (unsigned)f2bfu(fa2_.z) | ((unsigned)f2bfu(fa2_.w) << 16); \
            AV[6] = (unsigned)f2bfu(fa3_.x) | ((unsigned)f2bfu(fa3_.y) << 16); \
            AV[7] = (unsigned)f2bfu(fa3_.z) | ((unsigned)f2bfu(fa3_.w) << 16); \
            BV[0] = (unsigned)f2bfu(fb0_.x) | ((unsigned)f2bfu(fb0_.y) << 16); \
            BV[1] = (unsigned)f2bfu(fb0_.z) | ((unsigned)f2bfu(fb0_.w) << 16); \
            BV[2] = (unsigned)f2bfu(fb1_.x) | ((unsigned)f2bfu(fb1_.y) << 16); \
            BV[3] = (unsigned)f2bfu(fb1_.z) | ((unsigned)f2bfu(fb1_.w) << 16); \
            BV[4] = (unsigned)f2bfu(fb2_.x) | ((unsigned)f2bfu(fb2_.y) << 16); \
            BV[5] = (unsigned)f2bfu(fb2_.z) | ((unsigned)f2bfu(fb2_.w) << 16); \
            BV[6] = (unsigned)f2bfu(fb3_.x) | ((unsigned)f2bfu(fb3_.y) << 16); \
            BV[7] = (unsigned)f2bfu(fb3_.z) | ((unsigned)f2bfu(fb3_.w) << 16); \
        }                                                                     \
    } else {                                                                  \
        _Pragma("unroll")                                                     \
        for (int e_ = 0; e_ < 8; ++e_) { AV[e_] = 0u; BV[e_] = 0u; }          \
        _Pragma("unroll")                                                     \
        for (int e_ = 0; e_ < 16; ++e_) {                                     \
            int k_ = k0_ + e_;                                                \
            if (k_ < IN_) {                                                   \
                unsigned va_ = (unsigned)f2bfu(ldany(X,  arow + k_, isb));    \
                unsigned vb_ = (unsigned)f2bfu(ldany(W1, brow + k_, isb));    \
                AV[e_ >> 1] |= va_ << ((e_ & 1) * 16);                        \
                BV[e_ >> 1] |= vb_ << ((e_ & 1) * 16);                        \
            }                                                                 \
        }                                                                     \
    }                                                                         \
} while (0)

#define GA_STORE(AV, BV) do {                                                 \
    uint4 u0_; u0_.x = AV[0]; u0_.y = AV[1]; u0_.z = AV[2]; u0_.w = AV[3];    \
    uint4 u1_; u1_.x = AV[4]; u1_.y = AV[5]; u1_.z = AV[6]; u1_.w = AV[7];    \
    uint4 v0_; v0_.x = BV[0]; v0_.y = BV[1]; v0_.z = BV[2]; v0_.w = BV[3];    \
    uint4 v1_; v1_.x = BV[4]; v1_.y = BV[5]; v1_.z = BV[6]; v1_.w = BV[7];    \
    *(uint4*)asw       = u0_; *(uint4*)(asw + 8) = u1_;                       \
    *(uint4*)bsw       = v0_; *(uint4*)(bsw + 8) = v1_;                       \
} while (0)

#define GA_MFMA() do {                                                        \
    short8 af_[4], bf_[4];                                                    \
    _Pragma("unroll")                                                         \
    for (int i_ = 0; i_ < 4; ++i_) af_[i_] = *(const short8*)(As + aoff[i_]); \
    _Pragma("unroll")                                                         \
    for (int j_ = 0; j_ < 4; ++j_) bf_[j_] = *(const short8*)(Bs + boff[j_]); \
    _Pragma("unroll")                                                         \
    for (int i_ = 0; i_ < 4; ++i_)                                            \
        _Pragma("unroll")                                                     \
        for (int j_ = 0; j_ < 4; ++j_)                                        \
            acc[i_][j_] = __builtin_amdgcn_mfma_f32_16x16x32_bf16(            \
                af_[i_], bf_[j_], acc[i_][j_], 0, 0, 0);                      \
} while (0)

__global__ __launch_bounds__(256) void gemm_apre(
    const void* __restrict__ X, const void* __restrict__ W1,
    const us16* __restrict__ taun, us16* __restrict__ Apre)
{
    const bool isb = detect_bf16(taun);
    __shared__ __align__(16) us16 As[128 * LDP_];
    __shared__ __align__(16) us16 Bs[128 * LDP_];

    const int L  = blockIdx.x;
    const int mt = (L & 7) + ((L >> 6) << 3);
    const int nt = (L >> 3) & 7;
    if (mt >= NPAIR_ / 128) return;
    const int m0 = mt * 128, n0 = nt * 128;

    const int tid  = threadIdx.x;
    const int lane = tid & 63;
    const int w    = tid >> 6;
    const int wr   = w >> 1, wc = w & 1;
    const int l16  = lane & 15, quad = lane >> 4;
    const int ra   = tid >> 1;
    const int half16 = (tid & 1) * 16;

    f32x4 acc[4][4];
#pragma unroll
    for (int i = 0; i < 4; ++i)
#pragma unroll
        for (int j = 0; j < 4; ++j) acc[i][j] = (f32x4){0.f, 0.f, 0.f, 0.f};

    int aoff[4], boff[4];
#pragma unroll
    for (int i = 0; i < 4; ++i) {
        aoff[i] = (wr * 64 + i * 16 + l16) * LDP_ + quad * 8;
        boff[i] = (wc * 64 + i * 16 + l16) * LDP_ + quad * 8;
    }

    const long arow = (long)(m0 + ra) * IN_;
    const long brow = (long)(n0 + ra) * IN_;
    us16* asw = As + ra * LDP_ + half16;
    us16* bsw = Bs + ra * LDP_ + half16;

    unsigned av0[8], bv0[8], av1[8], bv1[8];
    GA_LOAD(0, av0, bv0);

    for (int ss = 0; ss < 11; ++ss) {
        __syncthreads();
        GA_STORE(av0, bv0);
        __syncthreads();
        GA_LOAD(2 * ss + 1, av1, bv1);
        GA_MFMA();
        __syncthreads();
        GA_STORE(av1, bv1);
        __syncthreads();
        if (ss < 10) GA_LOAD(2 * ss + 2, av0, bv0);
        GA_MFMA();
    }

#pragma unroll
    for (int i = 0; i < 4; ++i) {
#pragma unroll
        for (int j = 0; j < 4; ++j) {
            const int gm = m0 + wr * 64 + i * 16 + quad * 4;
            const int gn = n0 + wc * 64 + j * 16 + l16;
            us16* op = Apre + (long)gm * HK_ + gn;
#pragma unroll
            for (int r = 0; r < 4; ++r)
                op[(long)r * HK_] = f2bfu(acc[i][j][r]);
        }
    }
}

__global__ __launch_bounds__(64) void dhsfnn_wave(
    const us16* __restrict__ Apre,
    const void* __restrict__ b1,  const void* __restrict__ tau_n1,
    const void* __restrict__ tau_m1,
    const void* __restrict__ b2,  const void* __restrict__ tau_n2,
    const void* __restrict__ tau_m2,
    const void* __restrict__ Wr,  const void* __restrict__ br,
    const void* __restrict__ tau_mr,
    const us16* __restrict__ W2T,
    const int* __restrict__ warmup_p,
    void* __restrict__ out)
{
    const int lane = threadIdx.x;
    const int b    = blockIdx.x;
    const bool isb = detect_bf16((const us16*)tau_n1);
    const int wu   = *warmup_p;

    float be1[16], cb1[16], be2[16], cb2[16], d1[16], d2[16];
#pragma unroll
    for (int e = 0; e < 16; ++e) {
        const long gi = (long)lane * 16 + e;
        const float t1 = sigm(ldany(tau_n1, gi, isb));
        be1[e] = t1; cb1[e] = (1.f - t1) * ldany(b1, gi, isb);
        const float t2 = sigm(ldany(tau_n2, gi, isb));
        be2[e] = t2; cb2[e] = (1.f - t2) * ldany(b2, gi, isb);
        d1[e] = 0.f; d2[e] = 0.f;
    }
    float al1[4], al2[4], m1[4], s1[4], m2[4], s2[4];
#pragma unroll
    for (int j = 0; j < 4; ++j) {
        al1[j] = sigm(ldany(tau_m1, lane * 4 + j, isb));
        al2[j] = sigm(ldany(tau_m2, lane * 4 + j, isb));
        m1[j] = 0.f; s1[j] = 0.f; m2[j] = 0.f; s2[j] = 0.f;
    }
    float alr = 0.f, brv = 0.f;
    if (lane < O_) { alr = sigm(ldany(tau_mr, lane, isb)); brv = ldany(br, lane, isb); }
    float mrv = 0.f, accO = 0.f;

    const us16* ap = Apre + (long)b * T_ * HK_ + lane * 16;

    auto wstep = [&](int t, uint4 lo, uint4 hi) {
        float a[16];
        a[0]=bflo(lo.x);  a[1]=bfhi(lo.x);  a[2]=bflo(lo.y);  a[3]=bfhi(lo.y);
        a[4]=bflo(lo.z);  a[5]=bfhi(lo.z);  a[6]=bflo(lo.w);  a[7]=bfhi(lo.w);
        a[8]=bflo(hi.x);  a[9]=bfhi(hi.x);  a[10]=bflo(hi.y); a[11]=bfhi(hi.y);
        a[12]=bflo(hi.z); a[13]=bfhi(hi.z); a[14]=bflo(hi.w); a[15]=bfhi(hi.w);
#pragma unroll
        for (int e = 0; e < 16; ++e)
            d1[e] = be1[e] * d1[e] + cb1[e] + (1.f - be1[e]) * a[e];
        unsigned long long bal1[4];
#pragma unroll
        for (int j = 0; j < 4; ++j) {
            const float s = (d1[j*4+0] + d1[j*4+1]) + (d1[j*4+2] + d1[j*4+3]);
            m1[j] = m1[j] * al1[j] + (1.f - al1[j]) * s - s1[j];
            s1[j] = (m1[j] > 1.0f) ? 1.f : 0.f;
            bal1[j] = __ballot(s1[j] > 0.f);
        }
        if ((bal1[0] | bal1[1] | bal1[2] | bal1[3]) != 0ull) {
            float g[16];
#pragma unroll
            for (int e = 0; e < 16; ++e) g[e] = 0.f;
            for (int j2 = 0; j2 < 4; ++j2) {
                unsigned long long mm = bal1[j2];
                while (mm) {
                    const int i = __ffsll(mm) - 1; mm &= mm - 1;
                    const us16* wv = W2T + ((long)(i * 4 + j2) << 10) + lane * 16;
                    const uint4 wl = *(const uint4*)wv;
                    const uint4 wh = *(const uint4*)(wv + 8);
                    g[0]+=bflo(wl.x);  g[1]+=bfhi(wl.x);  g[2]+=bflo(wl.y);  g[3]+=bfhi(wl.y);
                    g[4]+=bflo(wl.z);  g[5]+=bfhi(wl.z);  g[6]+=bflo(wl.w);  g[7]+=bfhi(wl.w);
                    g[8]+=bflo(wh.x);  g[9]+=bfhi(wh.x);  g[10]+=bflo(wh.y); g[11]+=bfhi(wh.y);
                    g[12]+=bflo(wh.z); g[13]+=bfhi(wh.z); g[14]+=bflo(wh.w); g[15]+=bfhi(wh.w);
                }
            }
#pragma unroll
            for (int e = 0; e < 16; ++e)
                d2[e] = be2[e] * d2[e] + cb2[e] + (1.f - be2[e]) * g[e];
        } else {
#pragma unroll
            for (int e = 0; e < 16; ++e)
                d2[e] = be2[e] * d2[e] + cb2[e];
        }
        unsigned long long bal2[4];
#pragma unroll
        for (int j = 0; j < 4; ++j) {
            const float s = (d2[j*4+0] + d2[j*4+1]) + (d2[j*4+2] + d2[j*4+3]);
            m2[j] = m2[j] * al2[j] + (1.f - al2[j]) * s - s2[j];
            s2[j] = (m2[j] > 1.0f) ? 1.f : 0.f;
            bal2[j] = __ballot(s2[j] > 0.f);
        }
        if (lane < O_) {
            float sum = brv;
            if ((bal2[0] | bal2[1] | bal2[2] | bal2[3]) != 0ull) {
                for (int j2 = 0; j2 < 4; ++j2) {
                    unsigned long long mm = bal2[j2];
                    while (mm) {
                        const int i = __ffsll(mm) - 1; mm &= mm - 1;
                        sum += ldany(Wr, (long)lane * H_ + (i * 4 + j2), isb);
                    }
                }
            }
            mrv = alr * mrv + (1.f - alr) * sum;
            if (t >= wu) accO += mrv;
        }
    };

    uint4 q0a = *(const uint4*)(ap);
    uint4 q0b = *(const uint4*)(ap + 8);
    uint4 q1a = *(const uint4*)(ap + HK_);
    uint4 q1b = *(const uint4*)(ap + HK_ + 8);
    uint4 q2a = *(const uint4*)(ap + 2 * HK_);
    uint4 q2b = *(const uint4*)(ap + 2 * HK_ + 8);
    uint4 q3a = *(const uint4*)(ap + 3 * HK_);
    uint4 q3b = *(const uint4*)(ap + 3 * HK_ + 8);

    int t = 0;
    for (int it = 0; it < 62; ++it) {
        wstep(t + 0, q0a, q0b);
        q0a = *(const uint4*)(ap + (long)(t + 4) * HK_);
        q0b = *(const uint4*)(ap + (long)(t + 4) * HK_ + 8);
        wstep(t + 1, q1a, q1b);
        if (t + 5 < T_) {
            q1a = *(const uint4*)(ap + (long)(t + 5) * HK_);
            q1b = *(const uint4*)(ap + (long)(t + 5) * HK_ + 8);
        }
        wstep(t + 2, q2a, q2b);
        if (t + 6 < T_) {
            q2a = *(const uint4*)(ap + (long)(t + 6) * HK_);
            q2b = *(const uint4*)(ap + (long)(t + 6) * HK_ + 8);
        }
        wstep(t + 3, q3a, q3b);
        if (t + 7 < T_) {
            q3a = *(const uint4*)(ap + (long)(t + 7) * HK_);
            q3b = *(const uint4*)(ap + (long)(t + 7) * HK_ + 8);
        }
        t += 4;
    }
    wstep(248, q0a, q0b);
    wstep(249, q1a, q1b);

    if (lane < O_) {
        const float res = accO / (float)(T_ - wu);
        if (isb) ((us16*)out)[b * O_ + lane] = f2bfu(res);
        else     ((float*)out)[b * O_ + lane] = res;
    }
}

// ---------------------------------------------------------------------------
// Tier-3 fallback: no workspace at all (round-2 proven).
// ---------------------------------------------------------------------------
__global__ __launch_bounds__(256) void dhsfnn_fb(
    const void* __restrict__ x,  const void* __restrict__ W1,
    const void* __restrict__ b1, const void* __restrict__ tau_n1,
    const void* __restrict__ tau_m1,
    const void* __restrict__ W2, const void* __restrict__ b2,
    const void* __restrict__ tau_n2, const void* __restrict__ tau_m2,
    const void* __restrict__ Wr, const void* __restrict__ br,
    const void* __restrict__ tau_mr,
    const int* __restrict__ warmup_p,
    void* __restrict__ out)
{
    __shared__ us16 list1[1024];
    __shared__ us16 list2[256];
    __shared__ us16 list3[256];
    __shared__ int n1s, n2s, n3s;

    const int tid = threadIdx.x;
    const int b   = blockIdx.x;
    const int h   = tid;
    const bool isb = detect_bf16((const us16*)tau_n1);
    const int wu  = *warmup_p;

    const float be1_0 = sigm(ldany(tau_n1, 4 * h + 0, isb));
    const float be1_1 = sigm(ldany(tau_n1, 4 * h + 1, isb));
    const float be1_2 = sigm(ldany(tau_n1, 4 * h + 2, isb));
    const float be1_3 = sigm(ldany(tau_n1, 4 * h + 3, isb));
    const float bi1_0 = ldany(b1, 4 * h + 0, isb), bi1_1 = ldany(b1, 4 * h + 1, isb);
    const float bi1_2 = ldany(b1, 4 * h + 2, isb), bi1_3 = ldany(b1, 4 * h + 3, isb);
    const float al1 = sigm(ldany(tau_m1, h, isb));
    const float be2_0 = sigm(ldany(tau_n2, 4 * h + 0, isb));
    const float be2_1 = sigm(ldany(tau_n2, 4 * h + 1, isb));
    const float be2_2 = sigm(ldany(tau_n2, 4 * h + 2, isb));
    const float be2_3 = sigm(ldany(tau_n2, 4 * h + 3, isb));
    const float bi2_0 = ldany(b2, 4 * h + 0, isb), bi2_1 = ldany(b2, 4 * h + 1, isb);
    const float bi2_2 = ldany(b2, 4 * h + 2, isb), bi2_3 = ldany(b2, 4 * h + 3, isb);
    const float al2 = sigm(ldany(tau_m2, h, isb));
    float alr = 0.f, brv = 0.f;
    if (h < O_) { alr = sigm(ldany(tau_mr, h, isb)); brv = ldany(br, h, isb); }

    float d1_0 = 0.f, d1_1 = 0.f, d1_2 = 0.f, d1_3 = 0.f, m1v = 0.f, s1f = 0.f;
    float d2_0 = 0.f, d2_1 = 0.f, d2_2 = 0.f, d2_3 = 0.f, m2v = 0.f, s2f = 0.f;
    float mrv = 0.f, accO = 0.f;

    const long xbase = (long)b * T_ * IN_;
    float xv0 = ldany(x, xbase + tid, isb);
    float xv1 = ldany(x, xbase + tid + 256, isb);
    float xv2 = (tid + 512 < IN_) ? ldany(x, xbase + tid + 512, isb) : 0.f;

    for (int t = 0; t < T_; ++t) {
        const bool p0 = xv0 != 0.f, p1 = xv1 != 0.f, p2 = xv2 != 0.f;
        if (t + 1 < T_) {
            const long nbx = xbase + (long)(t + 1) * IN_;
            xv0 = ldany(x, nbx + tid, isb);
            xv1 = ldany(x, nbx + tid + 256, isb);
            xv2 = (tid + 512 < IN_) ? ldany(x, nbx + tid + 512, isb) : 0.f;
        }
        __syncthreads();
        if (tid == 0) { n1s = 0; n2s = 0; n3s = 0; }
        __syncthreads();
        if (p0) { int p = atomicAdd(&n1s, 1); list1[p & 1023] = (us16)tid; }
        if (p1) { int p = atomicAdd(&n1s, 1); list1[p & 1023] = (us16)(tid + 256); }
        if (p2) { int p = atomicAdd(&n1s, 1); list1[p & 1023] = (us16)(tid + 512); }
        __syncthreads();
        int n1 = n1s; n1 = (n1 < 1024) ? n1 : 1024;

        float a0 = 0.f, a1 = 0.f, a2 = 0.f, a3 = 0.f;
#pragma unroll 2
        for (int idx = 0; idx < n1; ++idx) {
            int i = rfl((int)list1[idx]);
            i = (i < IN_) ? i : (IN_ - 1);
            long r = (long)(h * 4) * IN_ + i;
            a0 += ldany(W1, r, isb);
            a1 += ldany(W1, r + IN_, isb);
            a2 += ldany(W1, r + 2 * IN_, isb);
            a3 += ldany(W1, r + 3 * IN_, isb);
        }
        d1_0 = be1_0 * d1_0 + (1.f - be1_0) * (bi1_0 + a0);
        d1_1 = be1_1 * d1_1 + (1.f - be1_1) * (bi1_1 + a1);
        d1_2 = be1_2 * d1_2 + (1.f - be1_2) * (bi1_2 + a2);
        d1_3 = be1_3 * d1_3 + (1.f - be1_3) * (bi1_3 + a3);
        m1v = m1v * al1 + (1.f - al1) * (d1_0 + d1_1 + d1_2 + d1_3) - s1f;
        s1f = (m1v > 1.0f) ? 1.f : 0.f;

        if (s1f > 0.f) { int p = atomicAdd(&n2s, 1); list2[p & 255] = (us16)tid; }
        __syncthreads();
        int n2 = n2s; n2 = (n2 < 256) ? n2 : 256;

        a0 = 0.f; a1 = 0.f; a2 = 0.f; a3 = 0.f;
#pragma unroll 2
        for (int idx = 0; idx < n2; ++idx) {
            int i = rfl((int)list2[idx]);
            i = (i < H_) ? i : (H_ - 1);
            long r = (long)(h * 4) * H_ + i;
            a0 += ldany(W2, r, isb);
            a1 += ldany(W2, r + H_, isb);
            a2 += ldany(W2, r + 2 * H_, isb);
            a3 += ldany(W2, r + 3 * H_, isb);
        }
        d2_0 = be2_0 * d2_0 + (1.f - be2_0) * (bi2_0 + a0);
        d2_1 = be2_1 * d2_1 + (1.f - be2_1) * (bi2_1 + a1);
        d2_2 = be2_2 * d2_2 + (1.f - be2_2) * (bi2_2 + a2);
        d2_3 = be2_3 * d2_3 + (1.f - be2_3) * (bi2_3 + a3);
        m2v = m2v * al2 + (1.f - al2) * (d2_0 + d2_1 + d2_2 + d2_3) - s2f;
        s2f = (m2v > 1.0f) ? 1.f : 0.f;

        if (s2f > 0.f) { int p = atomicAdd(&n3s, 1); list3[p & 255] = (us16)tid; }
        __syncthreads();
        int n3 = n3s; n3 = (n3 < 256) ? n3 : 256;

        if (h < O_) {
            float sum = brv;
            for (int idx = 0; idx < n3; ++idx) {
                int j = (int)list3[idx];
                j = (j < H_) ? j : (H_ - 1);
                sum += ldany(Wr, (long)h * H_ + j, isb);
            }
            mrv = alr * mrv + (1.f - alr) * sum;
            if (t >= wu) accO += mrv;
        }
    }
    if (h < O_) {
        float res = accO / (float)(T_ - wu);
        if (isb) ((us16*)out)[b * O_ + h] = f2bfu(res);
        else     ((float*)out)[b * O_ + h] = res;
    }
}

// ---------------------------------------------------------------------------
extern "C" void kernel_launch(void* const* d_in, const int* in_sizes, int n_in,
                              void* d_out, int out_size, void* d_ws, size_t ws_size,
                              hipStream_t stream) {
    const void* x      = d_in[0];
    const void* W1     = d_in[1];
    const void* b1     = d_in[2];
    const void* tau_n1 = d_in[3];
    const void* tau_m1 = d_in[4];
    const void* W2     = d_in[5];
    const void* b2     = d_in[6];
    const void* tau_n2 = d_in[7];
    const void* tau_m2 = d_in[8];
    const void* Wr     = d_in[9];
    const void* br     = d_in[10];
    const void* tau_mr = d_in[11];
    const int*  warmup = (const int*)d_in[12];

    const size_t w2t_bytes  = (size_t)H_ * HK_ * 2;            //     524,288
    const size_t xbf_bytes  = (size_t)NPAIR_ * KP_ * 2;        //  90,112,000
    const size_t w1b_bytes  = (size_t)HK_ * KP_ * 2;           //   1,441,792
    const size_t apre_bytes = (size_t)NPAIR_ * HK_ * 2;        // 131,072,000

    const bool tier0 = (d_ws != nullptr &&
                        ws_size >= w2t_bytes + xbf_bytes + w1b_bytes + apre_bytes);
    const bool tier1 = (d_ws != nullptr && ws_size >= w2t_bytes + apre_bytes);

    dim3 blk(32, 8);
    if (tier0) {
        us16* W2T  = (us16*)d_ws;
        us16* Xbf  = (us16*)((char*)d_ws + w2t_bytes);
        us16* W1bf = (us16*)((char*)d_ws + w2t_bytes + xbf_bytes);
        us16* Apre = (us16*)((char*)d_ws + w2t_bytes + xbf_bytes + w1b_bytes);
        cvt_rows2<<<(NPAIR_ + HK_) / 4, 256, 0, stream>>>(
            x, W1, Xbf, W1bf, (const us16*)tau_n1);
        transpose_to_bf16<<<dim3((H_ + 31) / 32, (HK_ + 31) / 32), blk, 0, stream>>>(
            W2, W2T, HK_, H_, (const us16*)tau_n1);
        gemm_bf<<<4096, 256, 0, stream>>>(Xbf, W1bf, Apre);
        dhsfnn_pc<<<B_, 256, 0, stream>>>(
            Apre, b1, tau_n1, tau_m1, b2, tau_n2, tau_m2,
            Wr, br, tau_mr, W2T, warmup, d_out);
    } else if (tier1) {
        us16* W2T  = (us16*)d_ws;
        us16* Apre = (us16*)((char*)d_ws + w2t_bytes);
        transpose_to_bf16<<<dim3((H_ + 31) / 32, (HK_ + 31) / 32), blk, 0, stream>>>(
            W2, W2T, HK_, H_, (const us16*)tau_n1);
        gemm_apre<<<4096, 256, 0, stream>>>(x, W1, (const us16*)tau_n1, Apre);
        dhsfnn_wave<<<B_, 64, 0, stream>>>(
            Apre, b1, tau_n1, tau_m1, b2, tau_n2, tau_m2,
            Wr, br, tau_mr, W2T, warmup, d_out);
    } else {
        dhsfnn_fb<<<B_, 256, 0, stream>>>(x, W1, b1, tau_n1, tau_m1,
                                          W2, b2, tau_n2, tau_m2,
                                          Wr, br, tau_mr, warmup, d_out);
    }
}